// Round 2
// baseline (713.246 us; speedup 1.0000x reference)
//
#include <hip/hip_runtime.h>
#include <math.h>

#define EMB 512
#define H1 300
#define H2 100
#define NB 2
#define NN 256
#define MM 256

// ws layout (floats)
#define OFF_HAA 0
#define OFF_HAB (OFF_HAA + NB*NN*H1)
#define OFF_HBA (OFF_HAB + NB*NN*H1)
#define OFF_HBB (OFF_HBA + NB*NN*H1)
#define OFF_S   (OFF_HBB + NB*NN*H1)          // NB*NN*4 floats, atomically accumulated
#define OFF_CST (OFF_S + NB*NN*4)             // NB*32 floats

// ---------------------------------------------------------------------------
// Kernel 0: per-b constants from anchor points.
// cst[b*32 + ...]: [0..2]=c, [3..11]=Hinv(row-major), [12..14]=t0, [15]=cc,
//                  [16..18]=SnP (= sum norm2*P / M), [19]=Sn (= sum norm2 / M)
// ---------------------------------------------------------------------------
__global__ void k_const(const float* __restrict__ anchor_pts, float* __restrict__ cst)
{
    int b = blockIdx.x;
    int m = threadIdx.x;            // 256 threads
    float px = anchor_pts[b*3*MM + 0*MM + m];
    float py = anchor_pts[b*3*MM + 1*MM + m];
    float pz = anchor_pts[b*3*MM + 2*MM + m];
    float n2 = px*px + py*py + pz*pz;

    float v[13];
    v[0]=px; v[1]=py; v[2]=pz;
    v[3]=px*px; v[4]=px*py; v[5]=px*pz; v[6]=py*py; v[7]=py*pz; v[8]=pz*pz;
    v[9]=n2*px; v[10]=n2*py; v[11]=n2*pz; v[12]=n2;

    #pragma unroll
    for (int off = 32; off >= 1; off >>= 1) {
        #pragma unroll
        for (int i = 0; i < 13; i++) v[i] += __shfl_xor(v[i], off, 64);
    }
    __shared__ float red[4][13];
    int wave = threadIdx.x >> 6, lane = threadIdx.x & 63;
    if (lane == 0) {
        #pragma unroll
        for (int i = 0; i < 13; i++) red[wave][i] = v[i];
    }
    __syncthreads();
    if (threadIdx.x == 0) {
        float s[13];
        #pragma unroll
        for (int i = 0; i < 13; i++)
            s[i] = red[0][i] + red[1][i] + red[2][i] + red[3][i];
        const float invM = 1.0f / MM;
        float c0 = s[0]*invM, c1 = s[1]*invM, c2 = s[2]*invM;
        float Pxx = s[3]*invM, Pxy = s[4]*invM, Pxz = s[5]*invM;
        float Pyy = s[6]*invM, Pyz = s[7]*invM, Pzz = s[8]*invM;

        // H = -2*PPt_mean + 2*c c^T   (symmetric)
        float H00 = -2.0f*Pxx + 2.0f*c0*c0;
        float H01 = -2.0f*Pxy + 2.0f*c0*c1;
        float H02 = -2.0f*Pxz + 2.0f*c0*c2;
        float H11 = -2.0f*Pyy + 2.0f*c1*c1;
        float H12 = -2.0f*Pyz + 2.0f*c1*c2;
        float H22 = -2.0f*Pzz + 2.0f*c2*c2;
        float H10 = H01, H20 = H02, H21 = H12;

        float det = H00*(H11*H22 - H12*H21)
                  - H01*(H10*H22 - H12*H20)
                  + H02*(H10*H21 - H11*H20);
        float id = 1.0f / det;
        float i00 = (H11*H22 - H12*H21)*id;
        float i01 = (H02*H21 - H01*H22)*id;
        float i02 = (H01*H12 - H02*H11)*id;
        float i10 = (H12*H20 - H10*H22)*id;
        float i11 = (H00*H22 - H02*H20)*id;
        float i12 = (H02*H10 - H00*H12)*id;
        float i20 = (H10*H21 - H11*H20)*id;
        float i21 = (H01*H20 - H00*H21)*id;
        float i22 = (H00*H11 - H01*H10)*id;

        // t0[d] = -2 * (PPt_mean row d) . c
        float t0x = -2.0f*(Pxx*c0 + Pxy*c1 + Pxz*c2);
        float t0y = -2.0f*(Pxy*c0 + Pyy*c1 + Pyz*c2);
        float t0z = -2.0f*(Pxz*c0 + Pyz*c1 + Pzz*c2);
        float cc = c0*c0 + c1*c1 + c2*c2;

        float* C = cst + b*32;
        C[0]=c0; C[1]=c1; C[2]=c2;
        C[3]=i00; C[4]=i01; C[5]=i02;
        C[6]=i10; C[7]=i11; C[8]=i12;
        C[9]=i20; C[10]=i21; C[11]=i22;
        C[12]=t0x; C[13]=t0y; C[14]=t0z;
        C[15]=cc;
        C[16]=s[9]*invM; C[17]=s[10]*invM; C[18]=s[11]*invM; C[19]=s[12]*invM;
    }
}

// ---------------------------------------------------------------------------
// Kernel 1: first layer. out[b][n][h] = sum_f E[b][f][n] * W1[half*512+f][h]
// Grid: (64 n-tiles of 4, NB, 2 srcs). 256 threads.
// ---------------------------------------------------------------------------
__global__ __launch_bounds__(256) void k_hidden(
    const float* __restrict__ actE, const float* __restrict__ ancE,
    const float* __restrict__ W1, float* __restrict__ ws)
{
    int b = blockIdx.y, src = blockIdx.z;
    int n0 = blockIdx.x * 4;
    const float* E = (src == 0 ? actE : ancE) + b * EMB * NN;
    float* outA = ws + (src == 0 ? OFF_HAA : OFF_HBA) + b * NN * H1;
    float* outB = ws + (src == 0 ? OFF_HAB : OFF_HBB) + b * NN * H1;

    __shared__ float Elds[EMB * 4];            // [f][4]
    for (int idx = threadIdx.x; idx < EMB * 4; idx += 256) {
        int f = idx >> 2, i = idx & 3;
        Elds[idx] = E[f * NN + n0 + i];
    }
    __syncthreads();

    int tid = threadIdx.x;
    float acc[3][4];
    int   hh[3]; int half[3]; bool act[3];
    #pragma unroll
    for (int ci = 0; ci < 3; ci++) {
        int col = tid + 256 * ci;
        act[ci] = (col < 600);
        half[ci] = (col >= 300) ? 1 : 0;
        hh[ci] = col - half[ci] * 300;
        #pragma unroll
        for (int i = 0; i < 4; i++) acc[ci][i] = 0.0f;
    }
    const float* wp0 = W1 + half[0]*EMB*H1 + hh[0];
    const float* wp1 = W1 + half[1]*EMB*H1 + hh[1];
    const float* wp2 = W1 + half[2]*EMB*H1 + hh[2];

    for (int f = 0; f < EMB; f++) {
        float4 e = *(const float4*)&Elds[f * 4];
        if (act[0]) {
            float w = wp0[f * H1];
            acc[0][0] = fmaf(e.x, w, acc[0][0]);
            acc[0][1] = fmaf(e.y, w, acc[0][1]);
            acc[0][2] = fmaf(e.z, w, acc[0][2]);
            acc[0][3] = fmaf(e.w, w, acc[0][3]);
        }
        if (act[1]) {
            float w = wp1[f * H1];
            acc[1][0] = fmaf(e.x, w, acc[1][0]);
            acc[1][1] = fmaf(e.y, w, acc[1][1]);
            acc[1][2] = fmaf(e.z, w, acc[1][2]);
            acc[1][3] = fmaf(e.w, w, acc[1][3]);
        }
        if (act[2]) {
            float w = wp2[f * H1];
            acc[2][0] = fmaf(e.x, w, acc[2][0]);
            acc[2][1] = fmaf(e.y, w, acc[2][1]);
            acc[2][2] = fmaf(e.z, w, acc[2][2]);
            acc[2][3] = fmaf(e.w, w, acc[2][3]);
        }
    }
    #pragma unroll
    for (int ci = 0; ci < 3; ci++) {
        if (!act[ci]) continue;
        float* o = (half[ci] ? outB : outA);
        #pragma unroll
        for (int i = 0; i < 4; i++)
            o[(n0 + i) * H1 + hh[ci]] = acc[ci][i];
    }
}

// ---------------------------------------------------------------------------
// Kernel 2: pairwise MLP + softplus + per-(b,n) accumulation of R^2, R^2*P.
// Grid: (16 m-tiles, 16 n-tiles, NB). 256 threads = 16n x 16m pairs.
// ---------------------------------------------------------------------------
__global__ __launch_bounds__(256) void k_pair(
    const float* __restrict__ ws_h,
    const float* __restrict__ anchor_pts,
    const float* __restrict__ b1, const float* __restrict__ W2,
    const float* __restrict__ b2, const float* __restrict__ W3,
    const float* __restrict__ b3v,
    float* __restrict__ S)
{
    int b  = blockIdx.z;
    int n0 = blockIdx.y * 16, m0 = blockIdx.x * 16;
    int tid = threadIdx.x;
    int nl = tid >> 4, ml = tid & 15;

    __shared__ float X[16 * H1];
    __shared__ float Y[16 * H1];

    const float* srcX[2] = { ws_h + OFF_HAA + (b*NN + n0) * H1,    // pass0: hA_a[n]
                             ws_h + OFF_HAB + (b*NN + n0) * H1 };  // pass1: hA_b[n]
    const float* srcY[2] = { ws_h + OFF_HBB + (b*NN + m0) * H1,    // pass0: hB_b[m]
                             ws_h + OFF_HBA + (b*NN + m0) * H1 };  // pass1: hB_a[m]

    float b3 = b3v[0];
    float vsum = 0.0f;

    #pragma unroll
    for (int p = 0; p < 2; p++) {
        __syncthreads();
        for (int idx = tid; idx < 16 * H1; idx += 256) {
            X[idx] = srcX[p][idx];
            Y[idx] = srcY[p][idx];
        }
        __syncthreads();

        float g[H2];
        #pragma unroll
        for (int j = 0; j < H2; j++) g[j] = 0.0f;

        const float* xr = &X[nl * H1];
        const float* yr = &Y[ml * H1];
        for (int k = 0; k < H1; k++) {
            float h = xr[k] + yr[k] + b1[k];
            h = fmaxf(h, 0.0f);
            const float* w2r = &W2[k * H2];
            #pragma unroll
            for (int j = 0; j < H2; j++)
                g[j] = fmaf(h, w2r[j], g[j]);
        }
        float v = b3;
        #pragma unroll
        for (int j = 0; j < H2; j++)
            v = fmaf(fmaxf(g[j] + b2[j], 0.0f), W3[j], v);
        vsum += v;
    }

    float x = 0.5f * vsum;
    float R = fmaxf(x, 0.0f) + log1pf(expf(-fabsf(x)));   // stable softplus
    float r2 = R * R;

    int m = m0 + ml;
    float px = anchor_pts[b*3*MM + 0*MM + m];
    float py = anchor_pts[b*3*MM + 1*MM + m];
    float pz = anchor_pts[b*3*MM + 2*MM + m];

    float s0 = r2*px, s1 = r2*py, s2 = r2*pz, s3 = r2;
    #pragma unroll
    for (int off = 8; off >= 1; off >>= 1) {
        s0 += __shfl_xor(s0, off, 16);
        s1 += __shfl_xor(s1, off, 16);
        s2 += __shfl_xor(s2, off, 16);
        s3 += __shfl_xor(s3, off, 16);
    }
    if (ml == 0) {
        int n = n0 + nl;
        float* sp = S + (b*NN + n) * 4;
        atomicAdd(sp + 0, s0);
        atomicAdd(sp + 1, s1);
        atomicAdd(sp + 2, s2);
        atomicAdd(sp + 3, s3);
    }
}

// ---------------------------------------------------------------------------
// Kernel 3: finalize multilateration, write flow (B,3,N).
// ---------------------------------------------------------------------------
__global__ void k_final(const float* __restrict__ S, const float* __restrict__ cst,
                        const float* __restrict__ action_pts, float* __restrict__ out)
{
    int b = blockIdx.x;
    int n = threadIdx.x;
    const float* C = cst + b*32;
    float c0=C[0], c1=C[1], c2=C[2];
    float t0x=C[12], t0y=C[13], t0z=C[14];
    float cc=C[15];
    float SnP0=C[16], SnP1=C[17], SnP2=C[18], Sn=C[19];

    const float* sp = S + (b*NN + n) * 4;
    const float invM = 1.0f / MM;
    float a0 = SnP0 - sp[0]*invM;
    float a1 = SnP1 - sp[1]*invM;
    float a2 = SnP2 - sp[2]*invM;
    float mWd = Sn - sp[3]*invM;

    float f0 = a0 + t0x - mWd*c0 + 2.0f*cc*c0;
    float f1 = a1 + t0y - mWd*c1 + 2.0f*cc*c1;
    float f2 = a2 + t0z - mWd*c2 + 2.0f*cc*c2;

    float q0 = -(C[3]*f0 + C[4]*f1 + C[5]*f2);
    float q1 = -(C[6]*f0 + C[7]*f1 + C[8]*f2);
    float q2 = -(C[9]*f0 + C[10]*f1 + C[11]*f2);

    float p0 = q0 + c0, p1 = q1 + c1, p2 = q2 + c2;

    out[b*3*NN + 0*NN + n] = p0 - action_pts[b*3*NN + 0*NN + n];
    out[b*3*NN + 1*NN + n] = p1 - action_pts[b*3*NN + 1*NN + n];
    out[b*3*NN + 2*NN + n] = p2 - action_pts[b*3*NN + 2*NN + n];
}

extern "C" void kernel_launch(void* const* d_in, const int* in_sizes, int n_in,
                              void* d_out, int out_size, void* d_ws, size_t ws_size,
                              hipStream_t stream)
{
    const float* actE = (const float*)d_in[0];
    const float* ancE = (const float*)d_in[1];
    const float* actP = (const float*)d_in[2];
    const float* ancP = (const float*)d_in[3];
    const float* W1   = (const float*)d_in[4];
    const float* b1   = (const float*)d_in[5];
    const float* W2   = (const float*)d_in[6];
    const float* b2   = (const float*)d_in[7];
    const float* W3   = (const float*)d_in[8];
    const float* b3   = (const float*)d_in[9];
    float* ws  = (float*)d_ws;
    float* out = (float*)d_out;

    hipMemsetAsync(ws + OFF_S, 0, NB*NN*4*sizeof(float), stream);
    k_const<<<NB, 256, 0, stream>>>(ancP, ws + OFF_CST);
    k_hidden<<<dim3(64, NB, 2), 256, 0, stream>>>(actE, ancE, W1, ws);
    k_pair<<<dim3(16, 16, NB), 256, 0, stream>>>(ws, ancP, b1, W2, b2, W3, b3, ws + OFF_S);
    k_final<<<NB, 256, 0, stream>>>(ws + OFF_S, ws + OFF_CST, actP, out);
}

// Round 3
// 347.561 us; speedup vs baseline: 2.0521x; 2.0521x over previous
//
#include <hip/hip_runtime.h>
#include <math.h>

#define EMB 512
#define H1 300
#define H2 100
#define NB 2
#define NN 256
#define MM 256

// ws layout (floats)
#define OFF_HAA 0
#define OFF_HAB (OFF_HAA + NB*NN*H1)
#define OFF_HBA (OFF_HAB + NB*NN*H1)
#define OFF_HBB (OFF_HBA + NB*NN*H1)
#define OFF_S   (OFF_HBB + NB*NN*H1)          // NB*NN*4 floats, atomically accumulated
#define OFF_CST (OFF_S + NB*NN*4)             // NB*32 floats

// ---------------------------------------------------------------------------
// Kernel 0: per-b constants from anchor points.
// ---------------------------------------------------------------------------
__global__ void k_const(const float* __restrict__ anchor_pts, float* __restrict__ cst)
{
    int b = blockIdx.x;
    int m = threadIdx.x;            // 256 threads
    float px = anchor_pts[b*3*MM + 0*MM + m];
    float py = anchor_pts[b*3*MM + 1*MM + m];
    float pz = anchor_pts[b*3*MM + 2*MM + m];
    float n2 = px*px + py*py + pz*pz;

    float v[13];
    v[0]=px; v[1]=py; v[2]=pz;
    v[3]=px*px; v[4]=px*py; v[5]=px*pz; v[6]=py*py; v[7]=py*pz; v[8]=pz*pz;
    v[9]=n2*px; v[10]=n2*py; v[11]=n2*pz; v[12]=n2;

    #pragma unroll
    for (int off = 32; off >= 1; off >>= 1) {
        #pragma unroll
        for (int i = 0; i < 13; i++) v[i] += __shfl_xor(v[i], off, 64);
    }
    __shared__ float red[4][13];
    int wave = threadIdx.x >> 6, lane = threadIdx.x & 63;
    if (lane == 0) {
        #pragma unroll
        for (int i = 0; i < 13; i++) red[wave][i] = v[i];
    }
    __syncthreads();
    if (threadIdx.x == 0) {
        float s[13];
        #pragma unroll
        for (int i = 0; i < 13; i++)
            s[i] = red[0][i] + red[1][i] + red[2][i] + red[3][i];
        const float invM = 1.0f / MM;
        float c0 = s[0]*invM, c1 = s[1]*invM, c2 = s[2]*invM;
        float Pxx = s[3]*invM, Pxy = s[4]*invM, Pxz = s[5]*invM;
        float Pyy = s[6]*invM, Pyz = s[7]*invM, Pzz = s[8]*invM;

        float H00 = -2.0f*Pxx + 2.0f*c0*c0;
        float H01 = -2.0f*Pxy + 2.0f*c0*c1;
        float H02 = -2.0f*Pxz + 2.0f*c0*c2;
        float H11 = -2.0f*Pyy + 2.0f*c1*c1;
        float H12 = -2.0f*Pyz + 2.0f*c1*c2;
        float H22 = -2.0f*Pzz + 2.0f*c2*c2;
        float H10 = H01, H20 = H02, H21 = H12;

        float det = H00*(H11*H22 - H12*H21)
                  - H01*(H10*H22 - H12*H20)
                  + H02*(H10*H21 - H11*H20);
        float id = 1.0f / det;
        float i00 = (H11*H22 - H12*H21)*id;
        float i01 = (H02*H21 - H01*H22)*id;
        float i02 = (H01*H12 - H02*H11)*id;
        float i10 = (H12*H20 - H10*H22)*id;
        float i11 = (H00*H22 - H02*H20)*id;
        float i12 = (H02*H10 - H00*H12)*id;
        float i20 = (H10*H21 - H11*H20)*id;
        float i21 = (H01*H20 - H00*H21)*id;
        float i22 = (H00*H11 - H01*H10)*id;

        float t0x = -2.0f*(Pxx*c0 + Pxy*c1 + Pxz*c2);
        float t0y = -2.0f*(Pxy*c0 + Pyy*c1 + Pyz*c2);
        float t0z = -2.0f*(Pxz*c0 + Pyz*c1 + Pzz*c2);
        float cc = c0*c0 + c1*c1 + c2*c2;

        float* C = cst + b*32;
        C[0]=c0; C[1]=c1; C[2]=c2;
        C[3]=i00; C[4]=i01; C[5]=i02;
        C[6]=i10; C[7]=i11; C[8]=i12;
        C[9]=i20; C[10]=i21; C[11]=i22;
        C[12]=t0x; C[13]=t0y; C[14]=t0z;
        C[15]=cc;
        C[16]=s[9]*invM; C[17]=s[10]*invM; C[18]=s[11]*invM; C[19]=s[12]*invM;
    }
}

// ---------------------------------------------------------------------------
// Kernel 1: first layer as LDS-tiled SGEMM.
// out[b][n][h] = sum_f E[b][f][n] * W1[half*512+f][h%300]  (h in [0,600))
// Tile: 64 n x 32 h per 256-thread block, BK=32.
// Grid: (NN/64=4, ceil(600/32)=19, NB*2=4) = 304 blocks.
// ---------------------------------------------------------------------------
#define BN 64
#define BH 32
#define BK 32

__global__ __launch_bounds__(256) void k_hidden(
    const float* __restrict__ actE, const float* __restrict__ ancE,
    const float* __restrict__ W1, float* __restrict__ ws)
{
    int bs = blockIdx.z;
    int b = bs >> 1, src = bs & 1;
    int n0 = blockIdx.x * BN;
    int h0 = blockIdx.y * BH;
    const float* E = (src == 0 ? actE : ancE) + b * EMB * NN;
    float* outA = ws + (src == 0 ? OFF_HAA : OFF_HBA) + b * NN * H1;
    float* outB = ws + (src == 0 ? OFF_HAB : OFF_HBB) + b * NN * H1;

    __shared__ float Elds[BK][BN];   // [k][n]
    __shared__ float Wlds[BK][BH];   // [k][h]

    int tid = threadIdx.x;
    int tx = tid & 15;        // h-pair index: h = h0 + tx*2 + {0,1}
    int ty = tid >> 4;        // n-quad index: n = n0 + ty*4 + {0..3}

    float acc[4][2];
    #pragma unroll
    for (int i = 0; i < 4; i++) { acc[i][0] = 0.0f; acc[i][1] = 0.0f; }

    // E staging map: thread -> (k = tid>>4 and +16, n4 = (tid&15)*4)
    int ek  = tid >> 4;
    int en4 = (tid & 15) * 4;
    // W staging map: thread -> (k = tid>>3, h4 = (tid&7)*4), one float4
    int wk  = tid >> 3;
    int wh4 = (tid & 7) * 4;
    int gh  = h0 + wh4;                      // global combined h of the float4
    bool wvalid = (gh < 600);
    int whalf = (gh >= 300) ? 1 : 0;
    // W1 row-major [1024][300]; float4 never straddles rows or the 300 split
    const float* wsrc = W1 + (size_t)whalf * EMB * H1 + (gh - whalf * 300);

    for (int k0 = 0; k0 < EMB; k0 += BK) {
        float4 e0 = *(const float4*)&E[(k0 + ek) * NN + n0 + en4];
        float4 e1 = *(const float4*)&E[(k0 + ek + 16) * NN + n0 + en4];
        float4 wv = make_float4(0.f, 0.f, 0.f, 0.f);
        if (wvalid) wv = *(const float4*)&wsrc[(size_t)(k0 + wk) * H1];

        __syncthreads();                     // previous chunk's compute done
        *(float4*)&Elds[ek][en4]      = e0;
        *(float4*)&Elds[ek + 16][en4] = e1;
        *(float4*)&Wlds[wk][wh4]      = wv;
        __syncthreads();

        #pragma unroll
        for (int k = 0; k < BK; k++) {
            float4 ev = *(const float4*)&Elds[k][ty * 4];
            float2 wv2 = *(const float2*)&Wlds[k][tx * 2];
            acc[0][0] = fmaf(ev.x, wv2.x, acc[0][0]);
            acc[0][1] = fmaf(ev.x, wv2.y, acc[0][1]);
            acc[1][0] = fmaf(ev.y, wv2.x, acc[1][0]);
            acc[1][1] = fmaf(ev.y, wv2.y, acc[1][1]);
            acc[2][0] = fmaf(ev.z, wv2.x, acc[2][0]);
            acc[2][1] = fmaf(ev.z, wv2.y, acc[2][1]);
            acc[3][0] = fmaf(ev.w, wv2.x, acc[3][0]);
            acc[3][1] = fmaf(ev.w, wv2.y, acc[3][1]);
        }
    }

    #pragma unroll
    for (int i = 0; i < 4; i++) {
        int n = n0 + ty * 4 + i;
        #pragma unroll
        for (int j = 0; j < 2; j++) {
            int h = h0 + tx * 2 + j;
            if (h < 300)       outA[n * H1 + h]       = acc[i][j];
            else if (h < 600)  outB[n * H1 + h - 300] = acc[i][j];
        }
    }
}

// ---------------------------------------------------------------------------
// Kernel 2: pairwise MLP + softplus + per-(b,n) accumulation of R^2, R^2*P.
// Grid: (16 m-tiles, 16 n-tiles, NB). 256 threads = 16n x 16m pairs.
// ---------------------------------------------------------------------------
__global__ __launch_bounds__(256) void k_pair(
    const float* __restrict__ ws_h,
    const float* __restrict__ anchor_pts,
    const float* __restrict__ b1, const float* __restrict__ W2,
    const float* __restrict__ b2, const float* __restrict__ W3,
    const float* __restrict__ b3v,
    float* __restrict__ S)
{
    int b  = blockIdx.z;
    int n0 = blockIdx.y * 16, m0 = blockIdx.x * 16;
    int tid = threadIdx.x;
    int nl = tid >> 4, ml = tid & 15;

    __shared__ float X[16 * H1];
    __shared__ float Y[16 * H1];

    const float* srcX[2] = { ws_h + OFF_HAA + (b*NN + n0) * H1,    // pass0: hA_a[n]
                             ws_h + OFF_HAB + (b*NN + n0) * H1 };  // pass1: hA_b[n]
    const float* srcY[2] = { ws_h + OFF_HBB + (b*NN + m0) * H1,    // pass0: hB_b[m]
                             ws_h + OFF_HBA + (b*NN + m0) * H1 };  // pass1: hB_a[m]

    float b3 = b3v[0];
    float vsum = 0.0f;

    #pragma unroll
    for (int p = 0; p < 2; p++) {
        __syncthreads();
        for (int idx = tid; idx < 16 * H1; idx += 256) {
            X[idx] = srcX[p][idx];
            Y[idx] = srcY[p][idx];
        }
        __syncthreads();

        float g[H2];
        #pragma unroll
        for (int j = 0; j < H2; j++) g[j] = 0.0f;

        const float* xr = &X[nl * H1];
        const float* yr = &Y[ml * H1];
        for (int k = 0; k < H1; k++) {
            float h = xr[k] + yr[k] + b1[k];
            h = fmaxf(h, 0.0f);
            const float* w2r = &W2[k * H2];
            #pragma unroll
            for (int j = 0; j < H2; j++)
                g[j] = fmaf(h, w2r[j], g[j]);
        }
        float v = b3;
        #pragma unroll
        for (int j = 0; j < H2; j++)
            v = fmaf(fmaxf(g[j] + b2[j], 0.0f), W3[j], v);
        vsum += v;
    }

    float x = 0.5f * vsum;
    float R = fmaxf(x, 0.0f) + log1pf(expf(-fabsf(x)));   // stable softplus
    float r2 = R * R;

    int m = m0 + ml;
    float px = anchor_pts[b*3*MM + 0*MM + m];
    float py = anchor_pts[b*3*MM + 1*MM + m];
    float pz = anchor_pts[b*3*MM + 2*MM + m];

    float s0 = r2*px, s1 = r2*py, s2 = r2*pz, s3 = r2;
    #pragma unroll
    for (int off = 8; off >= 1; off >>= 1) {
        s0 += __shfl_xor(s0, off, 16);
        s1 += __shfl_xor(s1, off, 16);
        s2 += __shfl_xor(s2, off, 16);
        s3 += __shfl_xor(s3, off, 16);
    }
    if (ml == 0) {
        int n = n0 + nl;
        float* sp = S + (b*NN + n) * 4;
        atomicAdd(sp + 0, s0);
        atomicAdd(sp + 1, s1);
        atomicAdd(sp + 2, s2);
        atomicAdd(sp + 3, s3);
    }
}

// ---------------------------------------------------------------------------
// Kernel 3: finalize multilateration, write flow (B,3,N).
// ---------------------------------------------------------------------------
__global__ void k_final(const float* __restrict__ S, const float* __restrict__ cst,
                        const float* __restrict__ action_pts, float* __restrict__ out)
{
    int b = blockIdx.x;
    int n = threadIdx.x;
    const float* C = cst + b*32;
    float c0=C[0], c1=C[1], c2=C[2];
    float t0x=C[12], t0y=C[13], t0z=C[14];
    float cc=C[15];
    float SnP0=C[16], SnP1=C[17], SnP2=C[18], Sn=C[19];

    const float* sp = S + (b*NN + n) * 4;
    const float invM = 1.0f / MM;
    float a0 = SnP0 - sp[0]*invM;
    float a1 = SnP1 - sp[1]*invM;
    float a2 = SnP2 - sp[2]*invM;
    float mWd = Sn - sp[3]*invM;

    float f0 = a0 + t0x - mWd*c0 + 2.0f*cc*c0;
    float f1 = a1 + t0y - mWd*c1 + 2.0f*cc*c1;
    float f2 = a2 + t0z - mWd*c2 + 2.0f*cc*c2;

    float q0 = -(C[3]*f0 + C[4]*f1 + C[5]*f2);
    float q1 = -(C[6]*f0 + C[7]*f1 + C[8]*f2);
    float q2 = -(C[9]*f0 + C[10]*f1 + C[11]*f2);

    float p0 = q0 + c0, p1 = q1 + c1, p2 = q2 + c2;

    out[b*3*NN + 0*NN + n] = p0 - action_pts[b*3*NN + 0*NN + n];
    out[b*3*NN + 1*NN + n] = p1 - action_pts[b*3*NN + 1*NN + n];
    out[b*3*NN + 2*NN + n] = p2 - action_pts[b*3*NN + 2*NN + n];
}

extern "C" void kernel_launch(void* const* d_in, const int* in_sizes, int n_in,
                              void* d_out, int out_size, void* d_ws, size_t ws_size,
                              hipStream_t stream)
{
    const float* actE = (const float*)d_in[0];
    const float* ancE = (const float*)d_in[1];
    const float* actP = (const float*)d_in[2];
    const float* ancP = (const float*)d_in[3];
    const float* W1   = (const float*)d_in[4];
    const float* b1   = (const float*)d_in[5];
    const float* W2   = (const float*)d_in[6];
    const float* b2   = (const float*)d_in[7];
    const float* W3   = (const float*)d_in[8];
    const float* b3   = (const float*)d_in[9];
    float* ws  = (float*)d_ws;
    float* out = (float*)d_out;

    hipMemsetAsync(ws + OFF_S, 0, NB*NN*4*sizeof(float), stream);
    k_const<<<NB, 256, 0, stream>>>(ancP, ws + OFF_CST);
    k_hidden<<<dim3(4, 19, 4), 256, 0, stream>>>(actE, ancE, W1, ws);
    k_pair<<<dim3(16, 16, NB), 256, 0, stream>>>(ws, ancP, b1, W2, b2, W3, b3, ws + OFF_S);
    k_final<<<NB, 256, 0, stream>>>(ws + OFF_S, ws + OFF_CST, actP, out);
}

// Round 4
// 155.648 us; speedup vs baseline: 4.5824x; 2.2330x over previous
//
#include <hip/hip_runtime.h>
#include <math.h>

#define EMB 512
#define H1 300
#define H2 100
#define NB 2
#define NN 256
#define MM 256

// ws layout (floats)
#define OFF_HAA 0
#define OFF_HAB (OFF_HAA + NB*NN*H1)
#define OFF_HBA (OFF_HAB + NB*NN*H1)
#define OFF_HBB (OFF_HBA + NB*NN*H1)
#define OFF_S   (OFF_HBB + NB*NN*H1)          // NB*NN*4 floats, atomic accum
#define OFF_CST (OFF_S + NB*NN*4)             // NB*32 floats
#define OFF_W2C (OFF_CST + 64)                // 10*112*32 bf16 = 17920 floats
#define OFF_B2P (OFF_W2C + 17920)             // 112 floats
#define OFF_W3P (OFF_B2P + 112)               // 112 floats

typedef __attribute__((ext_vector_type(8))) short bf16x8;
typedef __attribute__((ext_vector_type(4))) float f32x4;

static __device__ inline unsigned f2bfbits(float f) {
    union { float f; unsigned u; } v; v.f = f;
    return (v.u + 0x7fffu + ((v.u >> 16) & 1u)) >> 16;   // RNE
}

// ---------------------------------------------------------------------------
// Prep: W2 -> chunk-major bf16 [10][112][32] (zero-padded j>=100, k>=300),
// plus padded b2/W3 (zeros beyond 100).
// ---------------------------------------------------------------------------
__global__ void k_prep(const float* __restrict__ W2, const float* __restrict__ b2,
                       const float* __restrict__ W3, float* __restrict__ ws)
{
    unsigned short* W2c = (unsigned short*)(ws + OFF_W2C);
    int start = blockIdx.x * 256 + threadIdx.x;
    for (int idx = start; idx < 10*112*32; idx += gridDim.x * 256) {
        int c  = idx / 3584;
        int r  = idx - c * 3584;
        int j  = r >> 5;
        int kk = r & 31;
        int k  = c * 32 + kk;
        float v = (j < H2 && k < H1) ? W2[k * H2 + j] : 0.0f;
        W2c[idx] = (unsigned short)f2bfbits(v);
    }
    if (blockIdx.x == 0 && threadIdx.x < 112) {
        int j = threadIdx.x;
        ws[OFF_B2P + j] = (j < H2) ? b2[j] : 0.0f;
        ws[OFF_W3P + j] = (j < H2) ? W3[j] : 0.0f;
    }
}

// ---------------------------------------------------------------------------
// Kernel 0: per-b constants from anchor points.
// ---------------------------------------------------------------------------
__global__ void k_const(const float* __restrict__ anchor_pts, float* __restrict__ cst)
{
    int b = blockIdx.x;
    int m = threadIdx.x;            // 256 threads
    float px = anchor_pts[b*3*MM + 0*MM + m];
    float py = anchor_pts[b*3*MM + 1*MM + m];
    float pz = anchor_pts[b*3*MM + 2*MM + m];
    float n2 = px*px + py*py + pz*pz;

    float v[13];
    v[0]=px; v[1]=py; v[2]=pz;
    v[3]=px*px; v[4]=px*py; v[5]=px*pz; v[6]=py*py; v[7]=py*pz; v[8]=pz*pz;
    v[9]=n2*px; v[10]=n2*py; v[11]=n2*pz; v[12]=n2;

    #pragma unroll
    for (int off = 32; off >= 1; off >>= 1) {
        #pragma unroll
        for (int i = 0; i < 13; i++) v[i] += __shfl_xor(v[i], off, 64);
    }
    __shared__ float red[4][13];
    int wave = threadIdx.x >> 6, lane = threadIdx.x & 63;
    if (lane == 0) {
        #pragma unroll
        for (int i = 0; i < 13; i++) red[wave][i] = v[i];
    }
    __syncthreads();
    if (threadIdx.x == 0) {
        float s[13];
        #pragma unroll
        for (int i = 0; i < 13; i++)
            s[i] = red[0][i] + red[1][i] + red[2][i] + red[3][i];
        const float invM = 1.0f / MM;
        float c0 = s[0]*invM, c1 = s[1]*invM, c2 = s[2]*invM;
        float Pxx = s[3]*invM, Pxy = s[4]*invM, Pxz = s[5]*invM;
        float Pyy = s[6]*invM, Pyz = s[7]*invM, Pzz = s[8]*invM;

        float H00 = -2.0f*Pxx + 2.0f*c0*c0;
        float H01 = -2.0f*Pxy + 2.0f*c0*c1;
        float H02 = -2.0f*Pxz + 2.0f*c0*c2;
        float H11 = -2.0f*Pyy + 2.0f*c1*c1;
        float H12 = -2.0f*Pyz + 2.0f*c1*c2;
        float H22 = -2.0f*Pzz + 2.0f*c2*c2;
        float H10 = H01, H20 = H02, H21 = H12;

        float det = H00*(H11*H22 - H12*H21)
                  - H01*(H10*H22 - H12*H20)
                  + H02*(H10*H21 - H11*H20);
        float id = 1.0f / det;
        float i00 = (H11*H22 - H12*H21)*id;
        float i01 = (H02*H21 - H01*H22)*id;
        float i02 = (H01*H12 - H02*H11)*id;
        float i10 = (H12*H20 - H10*H22)*id;
        float i11 = (H00*H22 - H02*H20)*id;
        float i12 = (H02*H10 - H00*H12)*id;
        float i20 = (H10*H21 - H11*H20)*id;
        float i21 = (H01*H20 - H00*H21)*id;
        float i22 = (H00*H11 - H01*H10)*id;

        float t0x = -2.0f*(Pxx*c0 + Pxy*c1 + Pxz*c2);
        float t0y = -2.0f*(Pxy*c0 + Pyy*c1 + Pyz*c2);
        float t0z = -2.0f*(Pxz*c0 + Pyz*c1 + Pzz*c2);
        float cc = c0*c0 + c1*c1 + c2*c2;

        float* C = cst + b*32;
        C[0]=c0; C[1]=c1; C[2]=c2;
        C[3]=i00; C[4]=i01; C[5]=i02;
        C[6]=i10; C[7]=i11; C[8]=i12;
        C[9]=i20; C[10]=i21; C[11]=i22;
        C[12]=t0x; C[13]=t0y; C[14]=t0z;
        C[15]=cc;
        C[16]=s[9]*invM; C[17]=s[10]*invM; C[18]=s[11]*invM; C[19]=s[12]*invM;
    }
}

// ---------------------------------------------------------------------------
// Kernel 1: first layer as LDS-tiled SGEMM (+ b1 folded into action side).
// ---------------------------------------------------------------------------
#define BN 64
#define BH 32
#define BK 32

__global__ __launch_bounds__(256) void k_hidden(
    const float* __restrict__ actE, const float* __restrict__ ancE,
    const float* __restrict__ W1, const float* __restrict__ b1,
    float* __restrict__ ws)
{
    int bs = blockIdx.z;
    int b = bs >> 1, src = bs & 1;
    int n0 = blockIdx.x * BN;
    int h0 = blockIdx.y * BH;
    const float* E = (src == 0 ? actE : ancE) + b * EMB * NN;
    float* outA = ws + (src == 0 ? OFF_HAA : OFF_HBA) + b * NN * H1;
    float* outB = ws + (src == 0 ? OFF_HAB : OFF_HBB) + b * NN * H1;

    __shared__ float Elds[BK][BN];   // [k][n]
    __shared__ float Wlds[BK][BH];   // [k][h]

    int tid = threadIdx.x;
    int tx = tid & 15;        // h-pair: h = h0 + tx*2 + {0,1}
    int ty = tid >> 4;        // n-quad: n = n0 + ty*4 + {0..3}

    float acc[4][2];
    #pragma unroll
    for (int i = 0; i < 4; i++) { acc[i][0] = 0.0f; acc[i][1] = 0.0f; }

    int ek  = tid >> 4;
    int en4 = (tid & 15) * 4;
    int wk  = tid >> 3;
    int wh4 = (tid & 7) * 4;
    int gh  = h0 + wh4;
    bool wvalid = (gh < 600);
    int whalf = (gh >= 300) ? 1 : 0;
    const float* wsrc = W1 + (size_t)whalf * EMB * H1 + (gh - whalf * 300);

    for (int k0 = 0; k0 < EMB; k0 += BK) {
        float4 e0 = *(const float4*)&E[(k0 + ek) * NN + n0 + en4];
        float4 e1 = *(const float4*)&E[(k0 + ek + 16) * NN + n0 + en4];
        float4 wv = make_float4(0.f, 0.f, 0.f, 0.f);
        if (wvalid) wv = *(const float4*)&wsrc[(size_t)(k0 + wk) * H1];

        __syncthreads();
        *(float4*)&Elds[ek][en4]      = e0;
        *(float4*)&Elds[ek + 16][en4] = e1;
        *(float4*)&Wlds[wk][wh4]      = wv;
        __syncthreads();

        #pragma unroll
        for (int k = 0; k < BK; k++) {
            float4 ev = *(const float4*)&Elds[k][ty * 4];
            float2 wv2 = *(const float2*)&Wlds[k][tx * 2];
            acc[0][0] = fmaf(ev.x, wv2.x, acc[0][0]);
            acc[0][1] = fmaf(ev.x, wv2.y, acc[0][1]);
            acc[1][0] = fmaf(ev.y, wv2.x, acc[1][0]);
            acc[1][1] = fmaf(ev.y, wv2.y, acc[1][1]);
            acc[2][0] = fmaf(ev.z, wv2.x, acc[2][0]);
            acc[2][1] = fmaf(ev.z, wv2.y, acc[2][1]);
            acc[3][0] = fmaf(ev.w, wv2.x, acc[3][0]);
            acc[3][1] = fmaf(ev.w, wv2.y, acc[3][1]);
        }
    }

    #pragma unroll
    for (int i = 0; i < 4; i++) {
        int n = n0 + ty * 4 + i;
        #pragma unroll
        for (int j = 0; j < 2; j++) {
            int h = h0 + tx * 2 + j;
            if (h < 600) {
                int hh = (h < 300) ? h : h - 300;
                float bias = (src == 0) ? b1[hh] : 0.0f;   // fold b1 into action side
                float val = acc[i][j] + bias;
                if (h < 300) outA[n * H1 + hh] = val;
                else         outB[n * H1 + hh] = val;
            }
        }
    }
}

// ---------------------------------------------------------------------------
// Kernel 2: pairwise MLP via bf16 MFMA.
// Block = 16n x 16m = 256 pairs, 256 threads (4 waves).
// Pair row r = n_l*16 + m_l; ptile pt == n_l; wave w owns ptiles 4w..4w+3.
// K-loop: 10 chunks of 32 (K=300 zero-padded via zeroed W2 rows).
// ---------------------------------------------------------------------------
__global__ __launch_bounds__(256, 2) void k_pair(
    const float* __restrict__ ws_f,
    const float* __restrict__ ancP,
    float* __restrict__ S)
{
    int b  = blockIdx.z;
    int n0 = blockIdx.y * 16, m0 = blockIdx.x * 16;
    int tid = threadIdx.x;
    int lane = tid & 63, w = tid >> 6;
    int colj = lane & 15;        // MFMA col-in-tile / A-row-in-tile selector
    int quad = lane >> 4;

    __shared__ float hAfL[16 * 36];
    __shared__ float hBfL[16 * 36];
    __shared__ short Abf[256 * 40];      // bf16 A-tile, padded rows
    __shared__ short W2L[112 * 40];      // bf16 W2^T chunk [j][k]

    const unsigned short* W2c = (const unsigned short*)(ws_f + OFF_W2C);
    const float* b2p = ws_f + OFF_B2P;
    const float* w3p = ws_f + OFF_W3P;

    float b2v[7], w3v[7];
    #pragma unroll
    for (int jt = 0; jt < 7; jt++) {
        b2v[jt] = b2p[jt * 16 + colj];
        w3v[jt] = w3p[jt * 16 + colj];
    }
    float pxv[4], pyv[4], pzv[4];
    #pragma unroll
    for (int r = 0; r < 4; r++) {
        int m = m0 + quad * 4 + r;
        pxv[r] = ancP[b*3*MM + 0*MM + m];
        pyv[r] = ancP[b*3*MM + 1*MM + m];
        pzv[r] = ancP[b*3*MM + 2*MM + m];
    }

    const float* Xb[2] = { ws_f + OFF_HAA + (size_t)(b*NN + n0) * H1,
                           ws_f + OFF_HAB + (size_t)(b*NN + n0) * H1 };
    const float* Yb[2] = { ws_f + OFF_HBB + (size_t)(b*NN + m0) * H1,
                           ws_f + OFF_HBA + (size_t)(b*NN + m0) * H1 };

    // staging maps
    int sarr = tid >> 7;            // 0: X (n-side), 1: Y (m-side)
    int srow = (tid >> 3) & 15;
    int sseg = tid & 7;             // float4 segment within 32-k chunk
    int nl = tid >> 4, ml = tid & 15;

    float vsum[4][4];
    #pragma unroll
    for (int i = 0; i < 4; i++)
        #pragma unroll
        for (int r = 0; r < 4; r++) vsum[i][r] = 0.0f;

    #pragma unroll
    for (int p = 0; p < 2; p++) {
        f32x4 acc[4][7];
        #pragma unroll
        for (int i = 0; i < 4; i++)
            #pragma unroll
            for (int jt = 0; jt < 7; jt++)
                acc[i][jt] = (f32x4){0.f, 0.f, 0.f, 0.f};

        const float* Xp = Xb[p];
        const float* Yp = Yb[p];
        const float* ssrc = (sarr ? Yp : Xp) + srow * H1;

        for (int c = 0; c < 10; c++) {
            int k0 = c * 32;
            // ---- fetch staging data to regs (global, L2-hot) ----
            float4 sv = *(const float4*)&ssrc[k0 + sseg * 4];
            const uint4* wsrc4 = (const uint4*)W2c + c * 448;
            uint4 w0 = wsrc4[tid];
            uint4 w1 = wsrc4[(tid + 256) % 448];   // only tid<192 used

            __syncthreads();   // prior chunk fully consumed
            {
                float* dst = (sarr ? hBfL : hAfL) + srow * 36 + sseg * 4;
                *(float4*)dst = sv;
            }
            {
                int j = tid >> 2, q = tid & 3;
                *(uint4*)&W2L[j * 40 + q * 8] = w0;
                if (tid < 192) {
                    int u2 = tid + 256;
                    int j2 = u2 >> 2, q2 = u2 & 3;
                    *(uint4*)&W2L[j2 * 40 + q2 * 8] = w1;
                }
            }
            __syncthreads();

            // ---- h = relu(hA[n]+hB[m]) -> bf16 A-tile (row = tid) ----
            {
                const float* xa = hAfL + nl * 36;
                const float* xb = hBfL + ml * 36;
                short* arow = Abf + tid * 40;
                #pragma unroll
                for (int sg = 0; sg < 4; sg++) {
                    float4 a0 = *(const float4*)&xa[sg * 8];
                    float4 a1 = *(const float4*)&xa[sg * 8 + 4];
                    float4 c0 = *(const float4*)&xb[sg * 8];
                    float4 c1 = *(const float4*)&xb[sg * 8 + 4];
                    float h0 = fmaxf(a0.x + c0.x, 0.f);
                    float h1 = fmaxf(a0.y + c0.y, 0.f);
                    float h2 = fmaxf(a0.z + c0.z, 0.f);
                    float h3 = fmaxf(a0.w + c0.w, 0.f);
                    float h4 = fmaxf(a1.x + c1.x, 0.f);
                    float h5 = fmaxf(a1.y + c1.y, 0.f);
                    float h6 = fmaxf(a1.z + c1.z, 0.f);
                    float h7 = fmaxf(a1.w + c1.w, 0.f);
                    // k>=300 tail: W2 rows are zero, h finite -> contributes 0
                    uint4 pk;
                    pk.x = f2bfbits(h0) | (f2bfbits(h1) << 16);
                    pk.y = f2bfbits(h2) | (f2bfbits(h3) << 16);
                    pk.z = f2bfbits(h4) | (f2bfbits(h5) << 16);
                    pk.w = f2bfbits(h6) | (f2bfbits(h7) << 16);
                    *(uint4*)&arow[sg * 8] = pk;
                }
            }
            __syncthreads();

            // ---- MFMA: 4 ptiles x 7 jtiles per wave ----
            int koff = quad * 8;
            bf16x8 bfr[7];
            #pragma unroll
            for (int jt = 0; jt < 7; jt++)
                bfr[jt] = *(const bf16x8*)&W2L[(jt * 16 + colj) * 40 + koff];
            #pragma unroll
            for (int i = 0; i < 4; i++) {
                int pr = (w * 4 + i) * 16 + colj;
                bf16x8 af = *(const bf16x8*)&Abf[pr * 40 + koff];
                #pragma unroll
                for (int jt = 0; jt < 7; jt++)
                    acc[i][jt] = __builtin_amdgcn_mfma_f32_16x16x32_bf16(
                        af, bfr[jt], acc[i][jt], 0, 0, 0);
            }
        }

        // ---- layer 3 epilogue for this pass ----
        #pragma unroll
        for (int i = 0; i < 4; i++)
            #pragma unroll
            for (int jt = 0; jt < 7; jt++)
                #pragma unroll
                for (int r = 0; r < 4; r++)
                    vsum[i][r] = fmaf(fmaxf(acc[i][jt][r] + b2v[jt], 0.f),
                                      w3v[jt], vsum[i][r]);
    }

    // ---- reduce over cols (lane&15) ----
    #pragma unroll
    for (int i = 0; i < 4; i++)
        #pragma unroll
        for (int r = 0; r < 4; r++) {
            float v = vsum[i][r];
            v += __shfl_xor(v, 1, 16);
            v += __shfl_xor(v, 2, 16);
            v += __shfl_xor(v, 4, 16);
            v += __shfl_xor(v, 8, 16);
            vsum[i][r] = v;
        }

    // ---- softplus, R^2, m-reduction, atomics (ptile i -> n = n0+4w+i) ----
    #pragma unroll
    for (int i = 0; i < 4; i++) {
        float s0 = 0.f, s1 = 0.f, s2 = 0.f, s3 = 0.f;
        #pragma unroll
        for (int r = 0; r < 4; r++) {
            float x = 0.5f * vsum[i][r];
            float R = fmaxf(x, 0.f) + log1pf(expf(-fabsf(x)));
            float r2 = R * R;
            s0 = fmaf(r2, pxv[r], s0);
            s1 = fmaf(r2, pyv[r], s1);
            s2 = fmaf(r2, pzv[r], s2);
            s3 += r2;
        }
        s0 += __shfl_xor(s0, 16, 64); s0 += __shfl_xor(s0, 32, 64);
        s1 += __shfl_xor(s1, 16, 64); s1 += __shfl_xor(s1, 32, 64);
        s2 += __shfl_xor(s2, 16, 64); s2 += __shfl_xor(s2, 32, 64);
        s3 += __shfl_xor(s3, 16, 64); s3 += __shfl_xor(s3, 32, 64);
        if (lane == 0) {
            int n = n0 + w * 4 + i;
            float* sp = S + (b*NN + n) * 4;
            atomicAdd(sp + 0, s0);
            atomicAdd(sp + 1, s1);
            atomicAdd(sp + 2, s2);
            atomicAdd(sp + 3, s3);
        }
    }
}

// ---------------------------------------------------------------------------
// Kernel 3: finalize multilateration, write flow (B,3,N).
// ---------------------------------------------------------------------------
__global__ void k_final(const float* __restrict__ S, const float* __restrict__ cst,
                        const float* __restrict__ action_pts, float* __restrict__ out)
{
    int b = blockIdx.x;
    int n = threadIdx.x;
    const float* C = cst + b*32;
    float c0=C[0], c1=C[1], c2=C[2];
    float t0x=C[12], t0y=C[13], t0z=C[14];
    float cc=C[15];
    float SnP0=C[16], SnP1=C[17], SnP2=C[18], Sn=C[19];

    const float* sp = S + (b*NN + n) * 4;
    const float invM = 1.0f / MM;
    float a0 = SnP0 - sp[0]*invM;
    float a1 = SnP1 - sp[1]*invM;
    float a2 = SnP2 - sp[2]*invM;
    float mWd = Sn - sp[3]*invM;

    float f0 = a0 + t0x - mWd*c0 + 2.0f*cc*c0;
    float f1 = a1 + t0y - mWd*c1 + 2.0f*cc*c1;
    float f2 = a2 + t0z - mWd*c2 + 2.0f*cc*c2;

    float q0 = -(C[3]*f0 + C[4]*f1 + C[5]*f2);
    float q1 = -(C[6]*f0 + C[7]*f1 + C[8]*f2);
    float q2 = -(C[9]*f0 + C[10]*f1 + C[11]*f2);

    float p0 = q0 + c0, p1 = q1 + c1, p2 = q2 + c2;

    out[b*3*NN + 0*NN + n] = p0 - action_pts[b*3*NN + 0*NN + n];
    out[b*3*NN + 1*NN + n] = p1 - action_pts[b*3*NN + 1*NN + n];
    out[b*3*NN + 2*NN + n] = p2 - action_pts[b*3*NN + 2*NN + n];
}

extern "C" void kernel_launch(void* const* d_in, const int* in_sizes, int n_in,
                              void* d_out, int out_size, void* d_ws, size_t ws_size,
                              hipStream_t stream)
{
    const float* actE = (const float*)d_in[0];
    const float* ancE = (const float*)d_in[1];
    const float* actP = (const float*)d_in[2];
    const float* ancP = (const float*)d_in[3];
    const float* W1   = (const float*)d_in[4];
    const float* b1   = (const float*)d_in[5];
    const float* W2   = (const float*)d_in[6];
    const float* b2   = (const float*)d_in[7];
    const float* W3   = (const float*)d_in[8];
    const float* b3   = (const float*)d_in[9];
    float* ws  = (float*)d_ws;
    float* out = (float*)d_out;

    hipMemsetAsync(ws + OFF_S, 0, NB*NN*4*sizeof(float), stream);
    k_prep<<<16, 256, 0, stream>>>(W2, b2, W3, ws);
    k_const<<<NB, 256, 0, stream>>>(ancP, ws + OFF_CST);
    k_hidden<<<dim3(4, 19, 4), 256, 0, stream>>>(actE, ancE, W1, b1, ws);
    k_pair<<<dim3(16, 16, NB), 256, 0, stream>>>(ws, ancP, ws + OFF_S);
    k_final<<<NB, 256, 0, stream>>>(ws + OFF_S, ws + OFF_CST, actP, out);
}

// Round 5
// 132.486 us; speedup vs baseline: 5.3835x; 1.1748x over previous
//
#include <hip/hip_runtime.h>
#include <hip/hip_bf16.h>
#include <math.h>

#define EMB 512
#define H1 300
#define H2 100
#define NB 2
#define NN 256
#define MM 256

// ws layout (float units)
#define OFF_HAA 0
#define OFF_HAB 153600
#define OFF_HBA 307200
#define OFF_HBB 460800
#define OFF_S   614400   // NB*NN*4
#define OFF_CST 616448   // NB*32
#define OFF_W2C 616512   // 10*112*32 bf16 = 17920 floats
#define OFF_B2P 634432   // 112
#define OFF_W3P 634544   // 112
#define OFF_ET  634656   // 4*256*512 bf16 = 262144 floats
#define OFF_W1T 896800   // 640*512 bf16 = 163840 floats
#define OFF_V   1060640  // 2*NB*NN*MM floats

typedef __attribute__((ext_vector_type(8))) short bf16x8;
typedef __attribute__((ext_vector_type(4))) float f32x4;

static __device__ inline unsigned f2bfbits(float f) {
    union { float f; unsigned u; } v; v.f = f;
    return (v.u + 0x7fffu + ((v.u >> 16) & 1u)) >> 16;   // RNE
}
static __device__ inline unsigned pack_bf2(float a, float b) {
    union { __hip_bfloat162 h; unsigned u; } cv;
    cv.h = __float22bfloat162_rn(make_float2(a, b));
    return cv.u;
}

// ---------------------------------------------------------------------------
// Prep A: W2 -> chunk-major bf16 [10][112][32] (zero pad j>=100, k>=300),
// padded b2/W3.
// ---------------------------------------------------------------------------
__global__ void k_prep(const float* __restrict__ W2, const float* __restrict__ b2,
                       const float* __restrict__ W3, float* __restrict__ ws)
{
    unsigned short* W2c = (unsigned short*)(ws + OFF_W2C);
    int start = blockIdx.x * 256 + threadIdx.x;
    for (int idx = start; idx < 10*112*32; idx += gridDim.x * 256) {
        int c  = idx / 3584;
        int r  = idx - c * 3584;
        int j  = r >> 5;
        int kk = r & 31;
        int k  = c * 32 + kk;
        float v = (j < H2 && k < H1) ? W2[k * H2 + j] : 0.0f;
        W2c[idx] = (unsigned short)f2bfbits(v);
    }
    if (blockIdx.x == 0 && threadIdx.x < 112) {
        int j = threadIdx.x;
        ws[OFF_B2P + j] = (j < H2) ? b2[j] : 0.0f;
        ws[OFF_W3P + j] = (j < H2) ? W3[j] : 0.0f;
    }
}

// ---------------------------------------------------------------------------
// Prep B: W1 -> W1t[640][512] bf16 (h-major, zero pad h>=600).
// Grid (20 h-tiles, 16 f-tiles), 256 thr.
// ---------------------------------------------------------------------------
__global__ void k_prepw1(const float* __restrict__ W1, float* __restrict__ ws)
{
    __shared__ float Tf[32 * 36];
    unsigned short* W1t = (unsigned short*)(ws + OFF_W1T);
    int h0 = blockIdx.x * 32, f0 = blockIdx.y * 32;
    int tid = threadIdx.x;
    int fr = tid >> 3, hc4 = (tid & 7) * 4;
    int hg = h0 + hc4;
    float4 v = make_float4(0.f, 0.f, 0.f, 0.f);
    if (hg < 600) {
        int half = (hg >= 300) ? 1 : 0;
        int hh = hg - half * 300;
        v = *(const float4*)&W1[(size_t)(half * EMB + f0 + fr) * H1 + hh];
    }
    *(float4*)&Tf[fr * 36 + hc4] = v;
    __syncthreads();
    int hr = tid >> 3, f4 = (tid & 7) * 4;
    float v0 = Tf[(f4 + 0) * 36 + hr];
    float v1 = Tf[(f4 + 1) * 36 + hr];
    float v2 = Tf[(f4 + 2) * 36 + hr];
    float v3 = Tf[(f4 + 3) * 36 + hr];
    uint2 pk = make_uint2(pack_bf2(v0, v1), pack_bf2(v2, v3));
    *(uint2*)&W1t[(size_t)(h0 + hr) * EMB + f0 + f4] = pk;
}

// ---------------------------------------------------------------------------
// Prep C: E -> Et[bs][n][f] bf16 (transpose).  Grid (16 f-tiles, 8 n-tiles, 4).
// ---------------------------------------------------------------------------
__global__ void k_prepe(const float* __restrict__ actE, const float* __restrict__ ancE,
                        float* __restrict__ ws)
{
    __shared__ float Tf[32 * 36];
    unsigned short* Et = (unsigned short*)(ws + OFF_ET);
    int f0 = blockIdx.x * 32, n0 = blockIdx.y * 32;
    int bs = blockIdx.z, b = bs >> 1, src = bs & 1;
    const float* E = (src == 0 ? actE : ancE) + (size_t)b * EMB * NN;
    int tid = threadIdx.x;
    int r = tid >> 3, c4 = (tid & 7) * 4;
    float4 v = *(const float4*)&E[(size_t)(f0 + r) * NN + n0 + c4];
    *(float4*)&Tf[r * 36 + c4] = v;
    __syncthreads();
    int nr = tid >> 3, f4 = (tid & 7) * 4;
    float v0 = Tf[(f4 + 0) * 36 + nr];
    float v1 = Tf[(f4 + 1) * 36 + nr];
    float v2 = Tf[(f4 + 2) * 36 + nr];
    float v3 = Tf[(f4 + 3) * 36 + nr];
    uint2 pk = make_uint2(pack_bf2(v0, v1), pack_bf2(v2, v3));
    *(uint2*)&Et[((size_t)(bs * NN) + n0 + nr) * EMB + f0 + f4] = pk;
}

// ---------------------------------------------------------------------------
// Kernel 0: per-b constants from anchor points.
// ---------------------------------------------------------------------------
__global__ void k_const(const float* __restrict__ anchor_pts, float* __restrict__ cst)
{
    int b = blockIdx.x;
    int m = threadIdx.x;
    float px = anchor_pts[b*3*MM + 0*MM + m];
    float py = anchor_pts[b*3*MM + 1*MM + m];
    float pz = anchor_pts[b*3*MM + 2*MM + m];
    float n2 = px*px + py*py + pz*pz;

    float v[13];
    v[0]=px; v[1]=py; v[2]=pz;
    v[3]=px*px; v[4]=px*py; v[5]=px*pz; v[6]=py*py; v[7]=py*pz; v[8]=pz*pz;
    v[9]=n2*px; v[10]=n2*py; v[11]=n2*pz; v[12]=n2;

    #pragma unroll
    for (int off = 32; off >= 1; off >>= 1) {
        #pragma unroll
        for (int i = 0; i < 13; i++) v[i] += __shfl_xor(v[i], off, 64);
    }
    __shared__ float red[4][13];
    int wave = threadIdx.x >> 6, lane = threadIdx.x & 63;
    if (lane == 0) {
        #pragma unroll
        for (int i = 0; i < 13; i++) red[wave][i] = v[i];
    }
    __syncthreads();
    if (threadIdx.x == 0) {
        float s[13];
        #pragma unroll
        for (int i = 0; i < 13; i++)
            s[i] = red[0][i] + red[1][i] + red[2][i] + red[3][i];
        const float invM = 1.0f / MM;
        float c0 = s[0]*invM, c1 = s[1]*invM, c2 = s[2]*invM;
        float Pxx = s[3]*invM, Pxy = s[4]*invM, Pxz = s[5]*invM;
        float Pyy = s[6]*invM, Pyz = s[7]*invM, Pzz = s[8]*invM;

        float H00 = -2.0f*Pxx + 2.0f*c0*c0;
        float H01 = -2.0f*Pxy + 2.0f*c0*c1;
        float H02 = -2.0f*Pxz + 2.0f*c0*c2;
        float H11 = -2.0f*Pyy + 2.0f*c1*c1;
        float H12 = -2.0f*Pyz + 2.0f*c1*c2;
        float H22 = -2.0f*Pzz + 2.0f*c2*c2;
        float H10 = H01, H20 = H02, H21 = H12;

        float det = H00*(H11*H22 - H12*H21)
                  - H01*(H10*H22 - H12*H20)
                  + H02*(H10*H21 - H11*H20);
        float id = 1.0f / det;
        float i00 = (H11*H22 - H12*H21)*id;
        float i01 = (H02*H21 - H01*H22)*id;
        float i02 = (H01*H12 - H02*H11)*id;
        float i10 = (H12*H20 - H10*H22)*id;
        float i11 = (H00*H22 - H02*H20)*id;
        float i12 = (H02*H10 - H00*H12)*id;
        float i20 = (H10*H21 - H11*H20)*id;
        float i21 = (H01*H20 - H00*H21)*id;
        float i22 = (H00*H11 - H01*H10)*id;

        float t0x = -2.0f*(Pxx*c0 + Pxy*c1 + Pxz*c2);
        float t0y = -2.0f*(Pxy*c0 + Pyy*c1 + Pyz*c2);
        float t0z = -2.0f*(Pxz*c0 + Pyz*c1 + Pzz*c2);
        float cc = c0*c0 + c1*c1 + c2*c2;

        float* C = cst + b*32;
        C[0]=c0; C[1]=c1; C[2]=c2;
        C[3]=i00; C[4]=i01; C[5]=i02;
        C[6]=i10; C[7]=i11; C[8]=i12;
        C[9]=i20; C[10]=i21; C[11]=i22;
        C[12]=t0x; C[13]=t0y; C[14]=t0z;
        C[15]=cc;
        C[16]=s[9]*invM; C[17]=s[10]*invM; C[18]=s[11]*invM; C[19]=s[12]*invM;
    }
}

// ---------------------------------------------------------------------------
// Kernel 1: first layer via bf16 MFMA.
// Block tile: 32n x 64h. 4 waves: wave w -> ptile (w&1), jtiles {(w>>1)*2,+1}.
// Grid (8 n-tiles, 10 h-tiles, 4 bs). K = 16 chunks of 32.
// ---------------------------------------------------------------------------
__global__ __launch_bounds__(256) void k_hidden(
    float* __restrict__ ws, const float* __restrict__ b1)
{
    int bs = blockIdx.z, b = bs >> 1, src = bs & 1;
    int n0 = blockIdx.x * 32;
    int h0 = blockIdx.y * 64;
    const unsigned short* Et  = (const unsigned short*)(ws + OFF_ET)
                                + (size_t)(bs * NN) * EMB;
    const unsigned short* W1t = (const unsigned short*)(ws + OFF_W1T);
    float* outA = ws + (src == 0 ? OFF_HAA : OFF_HBA) + (size_t)b * NN * H1;
    float* outB = ws + (src == 0 ? OFF_HAB : OFF_HBB) + (size_t)b * NN * H1;

    __shared__ unsigned short EtL[32 * 40];
    __shared__ unsigned short W1tL[64 * 40];

    int tid = threadIdx.x;
    int lane = tid & 63, w = tid >> 6;
    int colj = lane & 15, quad = lane >> 4;
    int pt = w & 1, jt0 = (w >> 1) * 2;

    int erow = tid >> 3, es4 = (tid & 7) * 4;
    int wrow = tid >> 2, ws8 = (tid & 3) * 8;

    f32x4 acc[2];
    acc[0] = (f32x4){0.f,0.f,0.f,0.f};
    acc[1] = (f32x4){0.f,0.f,0.f,0.f};

    for (int c = 0; c < 16; c++) {
        int k0 = c * 32;
        uint2 ev = *(const uint2*)&Et[(size_t)(n0 + erow) * EMB + k0 + es4];
        uint4 wv = *(const uint4*)&W1t[(size_t)(h0 + wrow) * EMB + k0 + ws8];
        __syncthreads();
        *(uint2*)&EtL[erow * 40 + es4] = ev;
        *(uint4*)&W1tL[wrow * 40 + ws8] = wv;
        __syncthreads();

        bf16x8 af  = *(const bf16x8*)&EtL[(pt * 16 + colj) * 40 + quad * 8];
        bf16x8 bf0 = *(const bf16x8*)&W1tL[(jt0 * 16 + colj) * 40 + quad * 8];
        bf16x8 bf1 = *(const bf16x8*)&W1tL[((jt0 + 1) * 16 + colj) * 40 + quad * 8];
        acc[0] = __builtin_amdgcn_mfma_f32_16x16x32_bf16(af, bf0, acc[0], 0, 0, 0);
        acc[1] = __builtin_amdgcn_mfma_f32_16x16x32_bf16(af, bf1, acc[1], 0, 0, 0);
    }

    #pragma unroll
    for (int j2 = 0; j2 < 2; j2++) {
        int hg = h0 + (jt0 + j2) * 16 + colj;
        if (hg >= 600) continue;
        int hh = (hg < 300) ? hg : hg - 300;
        float* o = (hg < 300) ? outA : outB;
        float bias = (src == 0) ? b1[hh] : 0.0f;
        #pragma unroll
        for (int r = 0; r < 4; r++) {
            int n = n0 + pt * 16 + quad * 4 + r;
            o[(size_t)n * H1 + hh] = acc[j2][r] + bias;
        }
    }
}

// ---------------------------------------------------------------------------
// Kernel 2: pairwise MLP via bf16 MFMA, one pass per block.
// Grid (16 m-tiles, 16 n-tiles, NB*2: z = b*2+p). 256 thr = 4 waves.
// Wave w: ptiles (n_l = 4w+i), A-row m_l = colj; A-frag built in registers.
// Writes 0.5*(v_p + b3) into V[p][b][n][m].
// ---------------------------------------------------------------------------
__global__ __launch_bounds__(256) void k_pair(
    const float* __restrict__ ws_f, const float* __restrict__ b3p,
    float* __restrict__ V)
{
    int bz = blockIdx.z, b = bz >> 1, p = bz & 1;
    int n0 = blockIdx.y * 16, m0 = blockIdx.x * 16;
    int tid = threadIdx.x;
    int lane = tid & 63, w = tid >> 6;
    int colj = lane & 15, quad = lane >> 4;

    __shared__ float hAfL[16 * 36];
    __shared__ float hBfL[16 * 36];
    __shared__ short W2L[112 * 40];

    const unsigned short* W2c = (const unsigned short*)(ws_f + OFF_W2C);
    float b2v[7], w3v[7];
    #pragma unroll
    for (int jt = 0; jt < 7; jt++) {
        b2v[jt] = ws_f[OFF_B2P + jt * 16 + colj];
        w3v[jt] = ws_f[OFF_W3P + jt * 16 + colj];
    }
    float b3val = b3p[0];

    const float* srcX = ws_f + (p == 0 ? OFF_HAA : OFF_HAB) + (size_t)(b*NN + n0) * H1;
    const float* srcY = ws_f + (p == 0 ? OFF_HBB : OFF_HBA) + (size_t)(b*NN + m0) * H1;

    int sarr = tid >> 7;
    int srow = (tid >> 3) & 15;
    int sseg = tid & 7;
    const float* ssrc = (sarr ? srcY : srcX) + srow * H1;
    float* sdst = (sarr ? hBfL : hAfL) + srow * 36 + sseg * 4;

    f32x4 acc[4][7];
    #pragma unroll
    for (int i = 0; i < 4; i++)
        #pragma unroll
        for (int jt = 0; jt < 7; jt++)
            acc[i][jt] = (f32x4){0.f,0.f,0.f,0.f};

    for (int c = 0; c < 10; c++) {
        float4 sv = *(const float4*)&ssrc[c * 32 + sseg * 4];
        const uint4* wsrc4 = (const uint4*)W2c + c * 448;
        uint4 w0 = wsrc4[tid];
        uint4 w1 = wsrc4[(tid + 256) % 448];

        __syncthreads();
        *(float4*)sdst = sv;
        {
            int j = tid >> 2, q = tid & 3;
            *(uint4*)&W2L[j * 40 + q * 8] = w0;
            if (tid < 192) {
                int u2 = tid + 256;
                *(uint4*)&W2L[(u2 >> 2) * 40 + (u2 & 3) * 8] = w1;
            }
        }
        __syncthreads();

        // hB fragment (shared across the wave's 4 ptiles)
        float4 hb0 = *(const float4*)&hBfL[colj * 36 + quad * 8];
        float4 hb1 = *(const float4*)&hBfL[colj * 36 + quad * 8 + 4];
        // W2 fragments
        bf16x8 bfr[7];
        #pragma unroll
        for (int jt = 0; jt < 7; jt++)
            bfr[jt] = *(const bf16x8*)&W2L[(jt * 16 + colj) * 40 + quad * 8];

        #pragma unroll
        for (int i = 0; i < 4; i++) {
            const float* xa = &hAfL[(w * 4 + i) * 36 + quad * 8];
            float4 ha0 = *(const float4*)&xa[0];
            float4 ha1 = *(const float4*)&xa[4];
            union { unsigned u[4]; bf16x8 v; } af;
            af.u[0] = pack_bf2(fmaxf(ha0.x + hb0.x, 0.f), fmaxf(ha0.y + hb0.y, 0.f));
            af.u[1] = pack_bf2(fmaxf(ha0.z + hb0.z, 0.f), fmaxf(ha0.w + hb0.w, 0.f));
            af.u[2] = pack_bf2(fmaxf(ha1.x + hb1.x, 0.f), fmaxf(ha1.y + hb1.y, 0.f));
            af.u[3] = pack_bf2(fmaxf(ha1.z + hb1.z, 0.f), fmaxf(ha1.w + hb1.w, 0.f));
            #pragma unroll
            for (int jt = 0; jt < 7; jt++)
                acc[i][jt] = __builtin_amdgcn_mfma_f32_16x16x32_bf16(
                    af.v, bfr[jt], acc[i][jt], 0, 0, 0);
        }
    }

    // layer-3 epilogue
    float vsum[4][4];
    #pragma unroll
    for (int i = 0; i < 4; i++)
        #pragma unroll
        for (int r = 0; r < 4; r++) vsum[i][r] = 0.0f;
    #pragma unroll
    for (int i = 0; i < 4; i++)
        #pragma unroll
        for (int jt = 0; jt < 7; jt++)
            #pragma unroll
            for (int r = 0; r < 4; r++)
                vsum[i][r] = fmaf(fmaxf(acc[i][jt][r] + b2v[jt], 0.f),
                                  w3v[jt], vsum[i][r]);

    #pragma unroll
    for (int i = 0; i < 4; i++)
        #pragma unroll
        for (int r = 0; r < 4; r++) {
            float v = vsum[i][r];
            v += __shfl_xor(v, 1, 16);
            v += __shfl_xor(v, 2, 16);
            v += __shfl_xor(v, 4, 16);
            v += __shfl_xor(v, 8, 16);
            vsum[i][r] = v;
        }

    if (colj == 0) {
        #pragma unroll
        for (int i = 0; i < 4; i++) {
            int n = n0 + w * 4 + i;
            float4 o;
            o.x = 0.5f * (vsum[i][0] + b3val);
            o.y = 0.5f * (vsum[i][1] + b3val);
            o.z = 0.5f * (vsum[i][2] + b3val);
            o.w = 0.5f * (vsum[i][3] + b3val);
            *(float4*)&V[(((size_t)p * NB + b) * NN + n) * MM + m0 + quad * 4] = o;
        }
    }
}

// ---------------------------------------------------------------------------
// Kernel 2b: combine passes, softplus, reduce R^2 moments over m -> S.
// Grid (16 n-tiles, NB), 256 thr = 16n x 16 lanes.
// ---------------------------------------------------------------------------
__global__ void k_red(const float* __restrict__ V, const float* __restrict__ ancP,
                      float* __restrict__ S)
{
    int b = blockIdx.y;
    int n = blockIdx.x * 16 + (threadIdx.x >> 4);
    int ml = threadIdx.x & 15;
    const float* v0 = V + (((size_t)0 * NB + b) * NN + n) * MM;
    const float* v1 = V + (((size_t)1 * NB + b) * NN + n) * MM;
    float s0 = 0.f, s1 = 0.f, s2 = 0.f, s3 = 0.f;
    #pragma unroll
    for (int k = 0; k < 16; k++) {
        int m = ml + k * 16;
        float x = v0[m] + v1[m];
        float R = fmaxf(x, 0.f) + log1pf(expf(-fabsf(x)));
        float r2 = R * R;
        float px = ancP[b*3*MM + 0*MM + m];
        float py = ancP[b*3*MM + 1*MM + m];
        float pz = ancP[b*3*MM + 2*MM + m];
        s0 = fmaf(r2, px, s0);
        s1 = fmaf(r2, py, s1);
        s2 = fmaf(r2, pz, s2);
        s3 += r2;
    }
    #pragma unroll
    for (int off = 8; off >= 1; off >>= 1) {
        s0 += __shfl_xor(s0, off, 16);
        s1 += __shfl_xor(s1, off, 16);
        s2 += __shfl_xor(s2, off, 16);
        s3 += __shfl_xor(s3, off, 16);
    }
    if (ml == 0) {
        float4 o = make_float4(s0, s1, s2, s3);
        *(float4*)&S[(size_t)(b * NN + n) * 4] = o;
    }
}

// ---------------------------------------------------------------------------
// Kernel 3: finalize multilateration, write flow (B,3,N).
// ---------------------------------------------------------------------------
__global__ void k_final(const float* __restrict__ S, const float* __restrict__ cst,
                        const float* __restrict__ action_pts, float* __restrict__ out)
{
    int b = blockIdx.x;
    int n = threadIdx.x;
    const float* C = cst + b*32;
    float c0=C[0], c1=C[1], c2=C[2];
    float t0x=C[12], t0y=C[13], t0z=C[14];
    float cc=C[15];
    float SnP0=C[16], SnP1=C[17], SnP2=C[18], Sn=C[19];

    const float* sp = S + (b*NN + n) * 4;
    const float invM = 1.0f / MM;
    float a0 = SnP0 - sp[0]*invM;
    float a1 = SnP1 - sp[1]*invM;
    float a2 = SnP2 - sp[2]*invM;
    float mWd = Sn - sp[3]*invM;

    float f0 = a0 + t0x - mWd*c0 + 2.0f*cc*c0;
    float f1 = a1 + t0y - mWd*c1 + 2.0f*cc*c1;
    float f2 = a2 + t0z - mWd*c2 + 2.0f*cc*c2;

    float q0 = -(C[3]*f0 + C[4]*f1 + C[5]*f2);
    float q1 = -(C[6]*f0 + C[7]*f1 + C[8]*f2);
    float q2 = -(C[9]*f0 + C[10]*f1 + C[11]*f2);

    float p0 = q0 + c0, p1 = q1 + c1, p2 = q2 + c2;

    out[b*3*NN + 0*NN + n] = p0 - action_pts[b*3*NN + 0*NN + n];
    out[b*3*NN + 1*NN + n] = p1 - action_pts[b*3*NN + 1*NN + n];
    out[b*3*NN + 2*NN + n] = p2 - action_pts[b*3*NN + 2*NN + n];
}

extern "C" void kernel_launch(void* const* d_in, const int* in_sizes, int n_in,
                              void* d_out, int out_size, void* d_ws, size_t ws_size,
                              hipStream_t stream)
{
    const float* actE = (const float*)d_in[0];
    const float* ancE = (const float*)d_in[1];
    const float* actP = (const float*)d_in[2];
    const float* ancP = (const float*)d_in[3];
    const float* W1   = (const float*)d_in[4];
    const float* b1   = (const float*)d_in[5];
    const float* W2   = (const float*)d_in[6];
    const float* b2   = (const float*)d_in[7];
    const float* W3   = (const float*)d_in[8];
    const float* b3   = (const float*)d_in[9];
    float* ws  = (float*)d_ws;
    float* out = (float*)d_out;

    k_prep  <<<16, 256, 0, stream>>>(W2, b2, W3, ws);
    k_prepw1<<<dim3(20, 16), 256, 0, stream>>>(W1, ws);
    k_prepe <<<dim3(16, 8, 4), 256, 0, stream>>>(actE, ancE, ws);
    k_const <<<NB, 256, 0, stream>>>(ancP, ws + OFF_CST);
    k_hidden<<<dim3(8, 10, 4), 256, 0, stream>>>(ws, b1);
    k_pair  <<<dim3(16, 16, NB*2), 256, 0, stream>>>(ws, b3, ws + OFF_V);
    k_red   <<<dim3(16, NB), 256, 0, stream>>>(ws + OFF_V, ancP, ws + OFF_S);
    k_final <<<NB, 256, 0, stream>>>(ws + OFF_S, ws + OFF_CST, actP, out);
}

// Round 6
// 126.357 us; speedup vs baseline: 5.6447x; 1.0485x over previous
//
#include <hip/hip_runtime.h>
#include <hip/hip_bf16.h>
#include <math.h>

#define EMB 512
#define H1 300
#define H2 100
#define NB 2
#define NN 256
#define MM 256

// ws layout (float units)
#define OFF_HAA 0
#define OFF_HAB 153600
#define OFF_HBA 307200
#define OFF_HBB 460800
#define OFF_S   614400   // (unused now)
#define OFF_CST 616448   // NB*32
#define OFF_W2C 616512   // 10*112*32 bf16 = 17920 floats
#define OFF_B2P 634432   // 112
#define OFF_W3P 634544   // 112
#define OFF_ET  634656   // 4*256*512 bf16 = 262144 floats
#define OFF_W1T 896800   // 640*512 bf16 = 163840 floats
#define OFF_V   1060640  // 2*NB*NN*MM floats

typedef __attribute__((ext_vector_type(8))) short bf16x8;
typedef __attribute__((ext_vector_type(4))) float f32x4;

static __device__ inline unsigned f2bfbits(float f) {
    union { float f; unsigned u; } v; v.f = f;
    return (v.u + 0x7fffu + ((v.u >> 16) & 1u)) >> 16;   // RNE
}
static __device__ inline unsigned pack_bf2(float a, float b) {
    union { __hip_bfloat162 h; unsigned u; } cv;
    cv.h = __float22bfloat162_rn(make_float2(a, b));
    return cv.u;
}

// ---------------------------------------------------------------------------
// k_setup: all prep work in one launch, branch by block range.
//  blocks [0,320):    W1 -> W1t[640][512] bf16 (h-major, zero pad h>=600)
//  blocks [320,832):  E  -> Et[bs][n][f] bf16 (transpose)
//  blocks [832,848):  W2 -> chunk-major bf16 [10][112][32] + padded b2/W3
//  blocks [848,850):  per-b multilateration constants
// ---------------------------------------------------------------------------
__global__ __launch_bounds__(256) void k_setup(
    const float* __restrict__ W1, const float* __restrict__ W2,
    const float* __restrict__ b2, const float* __restrict__ W3,
    const float* __restrict__ actE, const float* __restrict__ ancE,
    const float* __restrict__ ancP, float* __restrict__ ws)
{
    __shared__ float Tf[32 * 36];
    __shared__ float red[4][13];
    int blk = blockIdx.x;
    int tid = threadIdx.x;

    if (blk < 320) {
        // ---- W1 transpose ----
        unsigned short* W1t = (unsigned short*)(ws + OFF_W1T);
        int h0 = (blk % 20) * 32, f0 = (blk / 20) * 32;
        int fr = tid >> 3, hc4 = (tid & 7) * 4;
        int hg = h0 + hc4;
        float4 v = make_float4(0.f, 0.f, 0.f, 0.f);
        if (hg < 600) {
            int half = (hg >= 300) ? 1 : 0;
            int hh = hg - half * 300;
            v = *(const float4*)&W1[(size_t)(half * EMB + f0 + fr) * H1 + hh];
        }
        *(float4*)&Tf[fr * 36 + hc4] = v;
        __syncthreads();
        int hr = tid >> 3, f4 = (tid & 7) * 4;
        float v0 = Tf[(f4 + 0) * 36 + hr];
        float v1 = Tf[(f4 + 1) * 36 + hr];
        float v2 = Tf[(f4 + 2) * 36 + hr];
        float v3 = Tf[(f4 + 3) * 36 + hr];
        uint2 pk = make_uint2(pack_bf2(v0, v1), pack_bf2(v2, v3));
        *(uint2*)&W1t[(size_t)(h0 + hr) * EMB + f0 + f4] = pk;
    } else if (blk < 832) {
        // ---- E transpose ----
        int i = blk - 320;
        unsigned short* Et = (unsigned short*)(ws + OFF_ET);
        int f0 = (i & 15) * 32;
        int n0 = ((i >> 4) & 7) * 32;
        int bs = i >> 7, b = bs >> 1, src = bs & 1;
        const float* E = (src == 0 ? actE : ancE) + (size_t)b * EMB * NN;
        int r = tid >> 3, c4 = (tid & 7) * 4;
        float4 v = *(const float4*)&E[(size_t)(f0 + r) * NN + n0 + c4];
        *(float4*)&Tf[r * 36 + c4] = v;
        __syncthreads();
        int nr = tid >> 3, f4 = (tid & 7) * 4;
        float v0 = Tf[(f4 + 0) * 36 + nr];
        float v1 = Tf[(f4 + 1) * 36 + nr];
        float v2 = Tf[(f4 + 2) * 36 + nr];
        float v3 = Tf[(f4 + 3) * 36 + nr];
        uint2 pk = make_uint2(pack_bf2(v0, v1), pack_bf2(v2, v3));
        *(uint2*)&Et[((size_t)(bs * NN) + n0 + nr) * EMB + f0 + f4] = pk;
    } else if (blk < 848) {
        // ---- W2 chunk-major bf16 + padded b2/W3 ----
        int i = blk - 832;
        unsigned short* W2c = (unsigned short*)(ws + OFF_W2C);
        int start = i * 256 + tid;
        for (int idx = start; idx < 10*112*32; idx += 16 * 256) {
            int c  = idx / 3584;
            int r  = idx - c * 3584;
            int j  = r >> 5;
            int kk = r & 31;
            int k  = c * 32 + kk;
            float v = (j < H2 && k < H1) ? W2[k * H2 + j] : 0.0f;
            W2c[idx] = (unsigned short)f2bfbits(v);
        }
        if (i == 0 && tid < 112) {
            int j = tid;
            ws[OFF_B2P + j] = (j < H2) ? b2[j] : 0.0f;
            ws[OFF_W3P + j] = (j < H2) ? W3[j] : 0.0f;
        }
    } else {
        // ---- per-b constants ----
        int b = blk - 848;
        float* cst = ws + OFF_CST;
        int m = tid;
        float px = ancP[b*3*MM + 0*MM + m];
        float py = ancP[b*3*MM + 1*MM + m];
        float pz = ancP[b*3*MM + 2*MM + m];
        float n2 = px*px + py*py + pz*pz;

        float v[13];
        v[0]=px; v[1]=py; v[2]=pz;
        v[3]=px*px; v[4]=px*py; v[5]=px*pz; v[6]=py*py; v[7]=py*pz; v[8]=pz*pz;
        v[9]=n2*px; v[10]=n2*py; v[11]=n2*pz; v[12]=n2;

        #pragma unroll
        for (int off = 32; off >= 1; off >>= 1) {
            #pragma unroll
            for (int q = 0; q < 13; q++) v[q] += __shfl_xor(v[q], off, 64);
        }
        int wave = tid >> 6, lane = tid & 63;
        if (lane == 0) {
            #pragma unroll
            for (int q = 0; q < 13; q++) red[wave][q] = v[q];
        }
        __syncthreads();
        if (tid == 0) {
            float s[13];
            #pragma unroll
            for (int q = 0; q < 13; q++)
                s[q] = red[0][q] + red[1][q] + red[2][q] + red[3][q];
            const float invM = 1.0f / MM;
            float c0 = s[0]*invM, c1 = s[1]*invM, c2 = s[2]*invM;
            float Pxx = s[3]*invM, Pxy = s[4]*invM, Pxz = s[5]*invM;
            float Pyy = s[6]*invM, Pyz = s[7]*invM, Pzz = s[8]*invM;

            float H00 = -2.0f*Pxx + 2.0f*c0*c0;
            float H01 = -2.0f*Pxy + 2.0f*c0*c1;
            float H02 = -2.0f*Pxz + 2.0f*c0*c2;
            float H11 = -2.0f*Pyy + 2.0f*c1*c1;
            float H12 = -2.0f*Pyz + 2.0f*c1*c2;
            float H22 = -2.0f*Pzz + 2.0f*c2*c2;
            float H10 = H01, H20 = H02, H21 = H12;

            float det = H00*(H11*H22 - H12*H21)
                      - H01*(H10*H22 - H12*H20)
                      + H02*(H10*H21 - H11*H20);
            float id = 1.0f / det;
            float i00 = (H11*H22 - H12*H21)*id;
            float i01 = (H02*H21 - H01*H22)*id;
            float i02 = (H01*H12 - H02*H11)*id;
            float i10 = (H12*H20 - H10*H22)*id;
            float i11 = (H00*H22 - H02*H20)*id;
            float i12 = (H02*H10 - H00*H12)*id;
            float i20 = (H10*H21 - H11*H20)*id;
            float i21 = (H01*H20 - H00*H21)*id;
            float i22 = (H00*H11 - H01*H10)*id;

            float t0x = -2.0f*(Pxx*c0 + Pxy*c1 + Pxz*c2);
            float t0y = -2.0f*(Pxy*c0 + Pyy*c1 + Pyz*c2);
            float t0z = -2.0f*(Pxz*c0 + Pyz*c1 + Pzz*c2);
            float cc = c0*c0 + c1*c1 + c2*c2;

            float* C = cst + b*32;
            C[0]=c0; C[1]=c1; C[2]=c2;
            C[3]=i00; C[4]=i01; C[5]=i02;
            C[6]=i10; C[7]=i11; C[8]=i12;
            C[9]=i20; C[10]=i21; C[11]=i22;
            C[12]=t0x; C[13]=t0y; C[14]=t0z;
            C[15]=cc;
            C[16]=s[9]*invM; C[17]=s[10]*invM; C[18]=s[11]*invM; C[19]=s[12]*invM;
        }
    }
}

// ---------------------------------------------------------------------------
// Kernel 1: first layer via bf16 MFMA.
// Tile 16n x 64h. 4 waves: wave w -> jtile w. Grid (16, 10, 4) = 640 blocks.
// K = 16 chunks of 32.
// ---------------------------------------------------------------------------
__global__ __launch_bounds__(256) void k_hidden(
    float* __restrict__ ws, const float* __restrict__ b1)
{
    int bs = blockIdx.z, b = bs >> 1, src = bs & 1;
    int n0 = blockIdx.x * 16;
    int h0 = blockIdx.y * 64;
    const unsigned short* Et  = (const unsigned short*)(ws + OFF_ET)
                                + (size_t)(bs * NN) * EMB;
    const unsigned short* W1t = (const unsigned short*)(ws + OFF_W1T);
    float* outA = ws + (src == 0 ? OFF_HAA : OFF_HBA) + (size_t)b * NN * H1;
    float* outB = ws + (src == 0 ? OFF_HAB : OFF_HBB) + (size_t)b * NN * H1;

    __shared__ unsigned short EtL[16 * 40];
    __shared__ unsigned short W1tL[64 * 40];

    int tid = threadIdx.x;
    int lane = tid & 63, w = tid >> 6;
    int colj = lane & 15, quad = lane >> 4;

    int er  = tid >> 4, ek2 = (tid & 15) * 2;
    int wr  = tid >> 2, wk8 = (tid & 3) * 8;

    f32x4 acc = (f32x4){0.f, 0.f, 0.f, 0.f};

    for (int c = 0; c < 16; c++) {
        int k0 = c * 32;
        unsigned ev = *(const unsigned*)&Et[(size_t)(n0 + er) * EMB + k0 + ek2];
        uint4 wv = *(const uint4*)&W1t[(size_t)(h0 + wr) * EMB + k0 + wk8];
        __syncthreads();
        *(unsigned*)&EtL[er * 40 + ek2] = ev;
        *(uint4*)&W1tL[wr * 40 + wk8] = wv;
        __syncthreads();
        bf16x8 af = *(const bf16x8*)&EtL[colj * 40 + quad * 8];
        bf16x8 bf = *(const bf16x8*)&W1tL[(w * 16 + colj) * 40 + quad * 8];
        acc = __builtin_amdgcn_mfma_f32_16x16x32_bf16(af, bf, acc, 0, 0, 0);
    }

    int hg = h0 + w * 16 + colj;
    if (hg < 600) {
        int hh = (hg < 300) ? hg : hg - 300;
        float* o = (hg < 300) ? outA : outB;
        float bias = (src == 0) ? b1[hh] : 0.0f;
        #pragma unroll
        for (int r = 0; r < 4; r++) {
            int n = n0 + quad * 4 + r;
            o[(size_t)n * H1 + hh] = acc[r] + bias;
        }
    }
}

// ---------------------------------------------------------------------------
// Kernel 2: pairwise MLP via bf16 MFMA, one pass per block (unchanged).
// Grid (16 m-tiles, 16 n-tiles, NB*2: z = b*2+p). 256 thr = 4 waves.
// ---------------------------------------------------------------------------
__global__ __launch_bounds__(256) void k_pair(
    const float* __restrict__ ws_f, const float* __restrict__ b3p,
    float* __restrict__ V)
{
    int bz = blockIdx.z, b = bz >> 1, p = bz & 1;
    int n0 = blockIdx.y * 16, m0 = blockIdx.x * 16;
    int tid = threadIdx.x;
    int lane = tid & 63, w = tid >> 6;
    int colj = lane & 15, quad = lane >> 4;

    __shared__ float hAfL[16 * 36];
    __shared__ float hBfL[16 * 36];
    __shared__ short W2L[112 * 40];

    const unsigned short* W2c = (const unsigned short*)(ws_f + OFF_W2C);
    float b2v[7], w3v[7];
    #pragma unroll
    for (int jt = 0; jt < 7; jt++) {
        b2v[jt] = ws_f[OFF_B2P + jt * 16 + colj];
        w3v[jt] = ws_f[OFF_W3P + jt * 16 + colj];
    }
    float b3val = b3p[0];

    const float* srcX = ws_f + (p == 0 ? OFF_HAA : OFF_HAB) + (size_t)(b*NN + n0) * H1;
    const float* srcY = ws_f + (p == 0 ? OFF_HBB : OFF_HBA) + (size_t)(b*NN + m0) * H1;

    int sarr = tid >> 7;
    int srow = (tid >> 3) & 15;
    int sseg = tid & 7;
    const float* ssrc = (sarr ? srcY : srcX) + srow * H1;
    float* sdst = (sarr ? hBfL : hAfL) + srow * 36 + sseg * 4;

    f32x4 acc[4][7];
    #pragma unroll
    for (int i = 0; i < 4; i++)
        #pragma unroll
        for (int jt = 0; jt < 7; jt++)
            acc[i][jt] = (f32x4){0.f,0.f,0.f,0.f};

    for (int c = 0; c < 10; c++) {
        float4 sv = *(const float4*)&ssrc[c * 32 + sseg * 4];
        const uint4* wsrc4 = (const uint4*)W2c + c * 448;
        uint4 w0 = wsrc4[tid];
        uint4 w1 = wsrc4[(tid + 256) % 448];

        __syncthreads();
        *(float4*)sdst = sv;
        {
            int j = tid >> 2, q = tid & 3;
            *(uint4*)&W2L[j * 40 + q * 8] = w0;
            if (tid < 192) {
                int u2 = tid + 256;
                *(uint4*)&W2L[(u2 >> 2) * 40 + (u2 & 3) * 8] = w1;
            }
        }
        __syncthreads();

        float4 hb0 = *(const float4*)&hBfL[colj * 36 + quad * 8];
        float4 hb1 = *(const float4*)&hBfL[colj * 36 + quad * 8 + 4];
        bf16x8 bfr[7];
        #pragma unroll
        for (int jt = 0; jt < 7; jt++)
            bfr[jt] = *(const bf16x8*)&W2L[(jt * 16 + colj) * 40 + quad * 8];

        #pragma unroll
        for (int i = 0; i < 4; i++) {
            const float* xa = &hAfL[(w * 4 + i) * 36 + quad * 8];
            float4 ha0 = *(const float4*)&xa[0];
            float4 ha1 = *(const float4*)&xa[4];
            union { unsigned u[4]; bf16x8 v; } af;
            af.u[0] = pack_bf2(fmaxf(ha0.x + hb0.x, 0.f), fmaxf(ha0.y + hb0.y, 0.f));
            af.u[1] = pack_bf2(fmaxf(ha0.z + hb0.z, 0.f), fmaxf(ha0.w + hb0.w, 0.f));
            af.u[2] = pack_bf2(fmaxf(ha1.x + hb1.x, 0.f), fmaxf(ha1.y + hb1.y, 0.f));
            af.u[3] = pack_bf2(fmaxf(ha1.z + hb1.z, 0.f), fmaxf(ha1.w + hb1.w, 0.f));
            #pragma unroll
            for (int jt = 0; jt < 7; jt++)
                acc[i][jt] = __builtin_amdgcn_mfma_f32_16x16x32_bf16(
                    af.v, bfr[jt], acc[i][jt], 0, 0, 0);
        }
    }

    float vsum[4][4];
    #pragma unroll
    for (int i = 0; i < 4; i++)
        #pragma unroll
        for (int r = 0; r < 4; r++) vsum[i][r] = 0.0f;
    #pragma unroll
    for (int i = 0; i < 4; i++)
        #pragma unroll
        for (int jt = 0; jt < 7; jt++)
            #pragma unroll
            for (int r = 0; r < 4; r++)
                vsum[i][r] = fmaf(fmaxf(acc[i][jt][r] + b2v[jt], 0.f),
                                  w3v[jt], vsum[i][r]);

    #pragma unroll
    for (int i = 0; i < 4; i++)
        #pragma unroll
        for (int r = 0; r < 4; r++) {
            float v = vsum[i][r];
            v += __shfl_xor(v, 1, 16);
            v += __shfl_xor(v, 2, 16);
            v += __shfl_xor(v, 4, 16);
            v += __shfl_xor(v, 8, 16);
            vsum[i][r] = v;
        }

    if (colj == 0) {
        #pragma unroll
        for (int i = 0; i < 4; i++) {
            int n = n0 + w * 4 + i;
            float4 o;
            o.x = 0.5f * (vsum[i][0] + b3val);
            o.y = 0.5f * (vsum[i][1] + b3val);
            o.z = 0.5f * (vsum[i][2] + b3val);
            o.w = 0.5f * (vsum[i][3] + b3val);
            *(float4*)&V[(((size_t)p * NB + b) * NN + n) * MM + m0 + quad * 4] = o;
        }
    }
}

// ---------------------------------------------------------------------------
// k_finish: combine passes, softplus, reduce R^2 moments over m, then
// multilaterate and write flow (B,3,N). Grid (16 n-tiles, NB), 256 thr.
// ---------------------------------------------------------------------------
__global__ void k_finish(const float* __restrict__ V, const float* __restrict__ ancP,
                         const float* __restrict__ cst, const float* __restrict__ actP,
                         float* __restrict__ out)
{
    int b = blockIdx.y;
    int n = blockIdx.x * 16 + (threadIdx.x >> 4);
    int ml = threadIdx.x & 15;
    const float* v0 = V + (((size_t)0 * NB + b) * NN + n) * MM;
    const float* v1 = V + (((size_t)1 * NB + b) * NN + n) * MM;
    float s0 = 0.f, s1 = 0.f, s2 = 0.f, s3 = 0.f;
    #pragma unroll
    for (int k = 0; k < 16; k++) {
        int m = ml + k * 16;
        float x = v0[m] + v1[m];
        float R = fmaxf(x, 0.f) + log1pf(expf(-fabsf(x)));
        float r2 = R * R;
        float px = ancP[b*3*MM + 0*MM + m];
        float py = ancP[b*3*MM + 1*MM + m];
        float pz = ancP[b*3*MM + 2*MM + m];
        s0 = fmaf(r2, px, s0);
        s1 = fmaf(r2, py, s1);
        s2 = fmaf(r2, pz, s2);
        s3 += r2;
    }
    #pragma unroll
    for (int off = 8; off >= 1; off >>= 1) {
        s0 += __shfl_xor(s0, off, 16);
        s1 += __shfl_xor(s1, off, 16);
        s2 += __shfl_xor(s2, off, 16);
        s3 += __shfl_xor(s3, off, 16);
    }
    if (ml == 0) {
        const float* C = cst + b*32;
        float c0=C[0], c1=C[1], c2=C[2];
        float t0x=C[12], t0y=C[13], t0z=C[14];
        float cc=C[15];
        float SnP0=C[16], SnP1=C[17], SnP2=C[18], Sn=C[19];

        const float invM = 1.0f / MM;
        float a0 = SnP0 - s0*invM;
        float a1 = SnP1 - s1*invM;
        float a2 = SnP2 - s2*invM;
        float mWd = Sn - s3*invM;

        float f0 = a0 + t0x - mWd*c0 + 2.0f*cc*c0;
        float f1 = a1 + t0y - mWd*c1 + 2.0f*cc*c1;
        float f2 = a2 + t0z - mWd*c2 + 2.0f*cc*c2;

        float q0 = -(C[3]*f0 + C[4]*f1 + C[5]*f2);
        float q1 = -(C[6]*f0 + C[7]*f1 + C[8]*f2);
        float q2 = -(C[9]*f0 + C[10]*f1 + C[11]*f2);

        float p0 = q0 + c0, p1 = q1 + c1, p2 = q2 + c2;

        out[b*3*NN + 0*NN + n] = p0 - actP[b*3*NN + 0*NN + n];
        out[b*3*NN + 1*NN + n] = p1 - actP[b*3*NN + 1*NN + n];
        out[b*3*NN + 2*NN + n] = p2 - actP[b*3*NN + 2*NN + n];
    }
}

extern "C" void kernel_launch(void* const* d_in, const int* in_sizes, int n_in,
                              void* d_out, int out_size, void* d_ws, size_t ws_size,
                              hipStream_t stream)
{
    const float* actE = (const float*)d_in[0];
    const float* ancE = (const float*)d_in[1];
    const float* actP = (const float*)d_in[2];
    const float* ancP = (const float*)d_in[3];
    const float* W1   = (const float*)d_in[4];
    const float* b1   = (const float*)d_in[5];
    const float* W2   = (const float*)d_in[6];
    const float* b2   = (const float*)d_in[7];
    const float* W3   = (const float*)d_in[8];
    const float* b3   = (const float*)d_in[9];
    float* ws  = (float*)d_ws;
    float* out = (float*)d_out;

    k_setup <<<850, 256, 0, stream>>>(W1, W2, b2, W3, actE, ancE, ancP, ws);
    k_hidden<<<dim3(16, 10, 4), 256, 0, stream>>>(ws, b1);
    k_pair  <<<dim3(16, 16, NB*2), 256, 0, stream>>>(ws, b3, ws + OFF_V);
    k_finish<<<dim3(16, NB), 256, 0, stream>>>(ws + OFF_V, ancP, ws + OFF_CST, actP, out);
}

// Round 7
// 125.392 us; speedup vs baseline: 5.6881x; 1.0077x over previous
//
#include <hip/hip_runtime.h>
#include <hip/hip_bf16.h>
#include <math.h>

#define EMB 512
#define H1 300
#define H2 100
#define NB 2
#define NN 256
#define MM 256

// ws layout (float units)
#define OFF_HAA 0
#define OFF_HAB 153600
#define OFF_HBA 307200
#define OFF_HBB 460800
#define OFF_CST 616448   // NB*32
#define OFF_W2C 616512   // 10*112*32 bf16 = 17920 floats
#define OFF_B2P 634432   // 112
#define OFF_W3P 634544   // 112
#define OFF_ET  634656   // 4*256*512 bf16 = 262144 floats
#define OFF_W1T 896800   // 640*512 bf16 = 163840 floats
#define OFF_V   1060640  // 2*NB*NN*MM floats

typedef __attribute__((ext_vector_type(8))) short bf16x8;
typedef __attribute__((ext_vector_type(4))) float f32x4;

static __device__ inline unsigned f2bfbits(float f) {
    union { float f; unsigned u; } v; v.f = f;
    return (v.u + 0x7fffu + ((v.u >> 16) & 1u)) >> 16;   // RNE
}
static __device__ inline unsigned pack_bf2(float a, float b) {
    union { __hip_bfloat162 h; unsigned u; } cv;
    cv.h = __float22bfloat162_rn(make_float2(a, b));
    return cv.u;
}

// ---------------------------------------------------------------------------
// k_setup: all prep work in one launch, branch by block range.
//  blocks [0,320):    W1 -> W1t[640][512] bf16 (h-major, zero pad h>=600)
//  blocks [320,832):  E  -> Et[bs][n][f] bf16 (transpose)
//  blocks [832,848):  W2 -> chunk-major bf16 [10][112][32] + padded b2/W3
//  blocks [848,850):  per-b multilateration constants
// ---------------------------------------------------------------------------
__global__ __launch_bounds__(256) void k_setup(
    const float* __restrict__ W1, const float* __restrict__ W2,
    const float* __restrict__ b2, const float* __restrict__ W3,
    const float* __restrict__ actE, const float* __restrict__ ancE,
    const float* __restrict__ ancP, float* __restrict__ ws)
{
    __shared__ float Tf[32 * 36];
    __shared__ float red[4][13];
    int blk = blockIdx.x;
    int tid = threadIdx.x;

    if (blk < 320) {
        // ---- W1 transpose ----
        unsigned short* W1t = (unsigned short*)(ws + OFF_W1T);
        int h0 = (blk % 20) * 32, f0 = (blk / 20) * 32;
        int fr = tid >> 3, hc4 = (tid & 7) * 4;
        int hg = h0 + hc4;
        float4 v = make_float4(0.f, 0.f, 0.f, 0.f);
        if (hg < 600) {
            int half = (hg >= 300) ? 1 : 0;
            int hh = hg - half * 300;
            v = *(const float4*)&W1[(size_t)(half * EMB + f0 + fr) * H1 + hh];
        }
        *(float4*)&Tf[fr * 36 + hc4] = v;
        __syncthreads();
        int hr = tid >> 3, f4 = (tid & 7) * 4;
        float v0 = Tf[(f4 + 0) * 36 + hr];
        float v1 = Tf[(f4 + 1) * 36 + hr];
        float v2 = Tf[(f4 + 2) * 36 + hr];
        float v3 = Tf[(f4 + 3) * 36 + hr];
        uint2 pk = make_uint2(pack_bf2(v0, v1), pack_bf2(v2, v3));
        *(uint2*)&W1t[(size_t)(h0 + hr) * EMB + f0 + f4] = pk;
    } else if (blk < 832) {
        // ---- E transpose ----
        int i = blk - 320;
        unsigned short* Et = (unsigned short*)(ws + OFF_ET);
        int f0 = (i & 15) * 32;
        int n0 = ((i >> 4) & 7) * 32;
        int bs = i >> 7, b = bs >> 1, src = bs & 1;
        const float* E = (src == 0 ? actE : ancE) + (size_t)b * EMB * NN;
        int r = tid >> 3, c4 = (tid & 7) * 4;
        float4 v = *(const float4*)&E[(size_t)(f0 + r) * NN + n0 + c4];
        *(float4*)&Tf[r * 36 + c4] = v;
        __syncthreads();
        int nr = tid >> 3, f4 = (tid & 7) * 4;
        float v0 = Tf[(f4 + 0) * 36 + nr];
        float v1 = Tf[(f4 + 1) * 36 + nr];
        float v2 = Tf[(f4 + 2) * 36 + nr];
        float v3 = Tf[(f4 + 3) * 36 + nr];
        uint2 pk = make_uint2(pack_bf2(v0, v1), pack_bf2(v2, v3));
        *(uint2*)&Et[((size_t)(bs * NN) + n0 + nr) * EMB + f0 + f4] = pk;
    } else if (blk < 848) {
        // ---- W2 chunk-major bf16 + padded b2/W3 ----
        int i = blk - 832;
        unsigned short* W2c = (unsigned short*)(ws + OFF_W2C);
        int start = i * 256 + tid;
        for (int idx = start; idx < 10*112*32; idx += 16 * 256) {
            int c  = idx / 3584;
            int r  = idx - c * 3584;
            int j  = r >> 5;
            int kk = r & 31;
            int k  = c * 32 + kk;
            float v = (j < H2 && k < H1) ? W2[k * H2 + j] : 0.0f;
            W2c[idx] = (unsigned short)f2bfbits(v);
        }
        if (i == 0 && tid < 112) {
            int j = tid;
            ws[OFF_B2P + j] = (j < H2) ? b2[j] : 0.0f;
            ws[OFF_W3P + j] = (j < H2) ? W3[j] : 0.0f;
        }
    } else {
        // ---- per-b constants ----
        int b = blk - 848;
        float* cst = ws + OFF_CST;
        int m = tid;
        float px = ancP[b*3*MM + 0*MM + m];
        float py = ancP[b*3*MM + 1*MM + m];
        float pz = ancP[b*3*MM + 2*MM + m];
        float n2 = px*px + py*py + pz*pz;

        float v[13];
        v[0]=px; v[1]=py; v[2]=pz;
        v[3]=px*px; v[4]=px*py; v[5]=px*pz; v[6]=py*py; v[7]=py*pz; v[8]=pz*pz;
        v[9]=n2*px; v[10]=n2*py; v[11]=n2*pz; v[12]=n2;

        #pragma unroll
        for (int off = 32; off >= 1; off >>= 1) {
            #pragma unroll
            for (int q = 0; q < 13; q++) v[q] += __shfl_xor(v[q], off, 64);
        }
        int wave = tid >> 6, lane = tid & 63;
        if (lane == 0) {
            #pragma unroll
            for (int q = 0; q < 13; q++) red[wave][q] = v[q];
        }
        __syncthreads();
        if (tid == 0) {
            float s[13];
            #pragma unroll
            for (int q = 0; q < 13; q++)
                s[q] = red[0][q] + red[1][q] + red[2][q] + red[3][q];
            const float invM = 1.0f / MM;
            float c0 = s[0]*invM, c1 = s[1]*invM, c2 = s[2]*invM;
            float Pxx = s[3]*invM, Pxy = s[4]*invM, Pxz = s[5]*invM;
            float Pyy = s[6]*invM, Pyz = s[7]*invM, Pzz = s[8]*invM;

            float H00 = -2.0f*Pxx + 2.0f*c0*c0;
            float H01 = -2.0f*Pxy + 2.0f*c0*c1;
            float H02 = -2.0f*Pxz + 2.0f*c0*c2;
            float H11 = -2.0f*Pyy + 2.0f*c1*c1;
            float H12 = -2.0f*Pyz + 2.0f*c1*c2;
            float H22 = -2.0f*Pzz + 2.0f*c2*c2;
            float H10 = H01, H20 = H02, H21 = H12;

            float det = H00*(H11*H22 - H12*H21)
                      - H01*(H10*H22 - H12*H20)
                      + H02*(H10*H21 - H11*H20);
            float id = 1.0f / det;
            float i00 = (H11*H22 - H12*H21)*id;
            float i01 = (H02*H21 - H01*H22)*id;
            float i02 = (H01*H12 - H02*H11)*id;
            float i10 = (H12*H20 - H10*H22)*id;
            float i11 = (H00*H22 - H02*H20)*id;
            float i12 = (H02*H10 - H00*H12)*id;
            float i20 = (H10*H21 - H11*H20)*id;
            float i21 = (H01*H20 - H00*H21)*id;
            float i22 = (H00*H11 - H01*H10)*id;

            float t0x = -2.0f*(Pxx*c0 + Pxy*c1 + Pxz*c2);
            float t0y = -2.0f*(Pxy*c0 + Pyy*c1 + Pyz*c2);
            float t0z = -2.0f*(Pxz*c0 + Pyz*c1 + Pzz*c2);
            float cc = c0*c0 + c1*c1 + c2*c2;

            float* C = cst + b*32;
            C[0]=c0; C[1]=c1; C[2]=c2;
            C[3]=i00; C[4]=i01; C[5]=i02;
            C[6]=i10; C[7]=i11; C[8]=i12;
            C[9]=i20; C[10]=i21; C[11]=i22;
            C[12]=t0x; C[13]=t0y; C[14]=t0z;
            C[15]=cc;
            C[16]=s[9]*invM; C[17]=s[10]*invM; C[18]=s[11]*invM; C[19]=s[12]*invM;
        }
    }
}

// ---------------------------------------------------------------------------
// Kernel 1: first layer via bf16 MFMA.
// Tile 16n x 64h. 4 waves: wave w -> jtile w. Grid (16, 10, 4) = 640 blocks.
// ---------------------------------------------------------------------------
__global__ __launch_bounds__(256) void k_hidden(
    float* __restrict__ ws, const float* __restrict__ b1)
{
    int bs = blockIdx.z, b = bs >> 1, src = bs & 1;
    int n0 = blockIdx.x * 16;
    int h0 = blockIdx.y * 64;
    const unsigned short* Et  = (const unsigned short*)(ws + OFF_ET)
                                + (size_t)(bs * NN) * EMB;
    const unsigned short* W1t = (const unsigned short*)(ws + OFF_W1T);
    float* outA = ws + (src == 0 ? OFF_HAA : OFF_HBA) + (size_t)b * NN * H1;
    float* outB = ws + (src == 0 ? OFF_HAB : OFF_HBB) + (size_t)b * NN * H1;

    __shared__ unsigned short EtL[16 * 40];
    __shared__ unsigned short W1tL[64 * 40];

    int tid = threadIdx.x;
    int lane = tid & 63, w = tid >> 6;
    int colj = lane & 15, quad = lane >> 4;

    int er  = tid >> 4, ek2 = (tid & 15) * 2;
    int wr  = tid >> 2, wk8 = (tid & 3) * 8;

    f32x4 acc = (f32x4){0.f, 0.f, 0.f, 0.f};

    for (int c = 0; c < 16; c++) {
        int k0 = c * 32;
        unsigned ev = *(const unsigned*)&Et[(size_t)(n0 + er) * EMB + k0 + ek2];
        uint4 wv = *(const uint4*)&W1t[(size_t)(h0 + wr) * EMB + k0 + wk8];
        __syncthreads();
        *(unsigned*)&EtL[er * 40 + ek2] = ev;
        *(uint4*)&W1tL[wr * 40 + wk8] = wv;
        __syncthreads();
        bf16x8 af = *(const bf16x8*)&EtL[colj * 40 + quad * 8];
        bf16x8 bf = *(const bf16x8*)&W1tL[(w * 16 + colj) * 40 + quad * 8];
        acc = __builtin_amdgcn_mfma_f32_16x16x32_bf16(af, bf, acc, 0, 0, 0);
    }

    int hg = h0 + w * 16 + colj;
    if (hg < 600) {
        int hh = (hg < 300) ? hg : hg - 300;
        float* o = (hg < 300) ? outA : outB;
        float bias = (src == 0) ? b1[hh] : 0.0f;
        #pragma unroll
        for (int r = 0; r < 4; r++) {
            int n = n0 + quad * 4 + r;
            o[(size_t)n * H1 + hh] = acc[r] + bias;
        }
    }
}

// ---------------------------------------------------------------------------
// Kernel 2 (v3): pairwise MLP via bf16 MFMA, one pass per block.
// hA/hB tiles fully staged into LDS once (stride 308, pad zeroed);
// W2 fragments read straight from global (L2/L3-resident, coalesced 1KB/instr);
// K-loop has ZERO barriers.
// Grid (16 m-tiles, 16 n-tiles, NB*2: z = b*2+p). 256 thr = 4 waves.
// ---------------------------------------------------------------------------
#define SH 308   // LDS row stride (floats): mult of 4 (b128 align), %32==20 (2-way max)

__global__ __launch_bounds__(256, 2) void k_pair(
    const float* __restrict__ ws_f, const float* __restrict__ b3p,
    float* __restrict__ V)
{
    int bz = blockIdx.z, b = bz >> 1, p = bz & 1;
    int n0 = blockIdx.y * 16, m0 = blockIdx.x * 16;
    int tid = threadIdx.x;
    int lane = tid & 63, w = tid >> 6;
    int colj = lane & 15, quad = lane >> 4;

    __shared__ float hAf[16 * SH];
    __shared__ float hBf[16 * SH];

    const unsigned short* W2c = (const unsigned short*)(ws_f + OFF_W2C);
    float b2v[7], w3v[7];
    #pragma unroll
    for (int jt = 0; jt < 7; jt++) {
        b2v[jt] = ws_f[OFF_B2P + jt * 16 + colj];
        w3v[jt] = ws_f[OFF_W3P + jt * 16 + colj];
    }
    float b3val = b3p[0];

    const float* srcX = ws_f + (p == 0 ? OFF_HAA : OFF_HAB) + (size_t)(b*NN + n0) * H1;
    const float* srcY = ws_f + (p == 0 ? OFF_HBB : OFF_HBA) + (size_t)(b*NN + m0) * H1;

    // Stage both tiles: per array 16 rows x 77 float4 (75 data + 2 pad) = 1232 slots.
    for (int idx = tid; idx < 2464; idx += 256) {
        int a = (idx >= 1232) ? 1 : 0;
        int k = idx - a * 1232;
        int row, c4;
        float4 v = make_float4(0.f, 0.f, 0.f, 0.f);
        if (k < 1200) {
            row = k / 75; c4 = k - row * 75;
            v = *(const float4*)&(a ? srcY : srcX)[row * H1 + c4 * 4];
        } else {
            int j = k - 1200;
            row = j >> 1; c4 = 75 + (j & 1);
        }
        float* dst = (a ? hBf : hAf) + row * SH + c4 * 4;
        *(float4*)dst = v;
    }
    __syncthreads();

    f32x4 acc[4][7];
    #pragma unroll
    for (int i = 0; i < 4; i++)
        #pragma unroll
        for (int jt = 0; jt < 7; jt++)
            acc[i][jt] = (f32x4){0.f,0.f,0.f,0.f};

    #pragma unroll
    for (int c = 0; c < 10; c++) {
        // W2 fragments direct from global (coalesced, L2-hot, zero rows for k>=300/j>=100)
        bf16x8 bfr[7];
        #pragma unroll
        for (int jt = 0; jt < 7; jt++)
            bfr[jt] = *(const bf16x8*)&W2c[c * 3584 + (jt * 16 + colj) * 32 + quad * 8];

        float4 hb0 = *(const float4*)&hBf[colj * SH + c * 32 + quad * 8];
        float4 hb1 = *(const float4*)&hBf[colj * SH + c * 32 + quad * 8 + 4];

        #pragma unroll
        for (int i = 0; i < 4; i++) {
            const float* xa = &hAf[(w * 4 + i) * SH + c * 32 + quad * 8];
            float4 ha0 = *(const float4*)&xa[0];
            float4 ha1 = *(const float4*)&xa[4];
            union { unsigned u[4]; bf16x8 v; } af;
            af.u[0] = pack_bf2(fmaxf(ha0.x + hb0.x, 0.f), fmaxf(ha0.y + hb0.y, 0.f));
            af.u[1] = pack_bf2(fmaxf(ha0.z + hb0.z, 0.f), fmaxf(ha0.w + hb0.w, 0.f));
            af.u[2] = pack_bf2(fmaxf(ha1.x + hb1.x, 0.f), fmaxf(ha1.y + hb1.y, 0.f));
            af.u[3] = pack_bf2(fmaxf(ha1.z + hb1.z, 0.f), fmaxf(ha1.w + hb1.w, 0.f));
            #pragma unroll
            for (int jt = 0; jt < 7; jt++)
                acc[i][jt] = __builtin_amdgcn_mfma_f32_16x16x32_bf16(
                    af.v, bfr[jt], acc[i][jt], 0, 0, 0);
        }
    }

    // layer-3 epilogue
    float vsum[4][4];
    #pragma unroll
    for (int i = 0; i < 4; i++)
        #pragma unroll
        for (int r = 0; r < 4; r++) vsum[i][r] = 0.0f;
    #pragma unroll
    for (int i = 0; i < 4; i++)
        #pragma unroll
        for (int jt = 0; jt < 7; jt++)
            #pragma unroll
            for (int r = 0; r < 4; r++)
                vsum[i][r] = fmaf(fmaxf(acc[i][jt][r] + b2v[jt], 0.f),
                                  w3v[jt], vsum[i][r]);

    #pragma unroll
    for (int i = 0; i < 4; i++)
        #pragma unroll
        for (int r = 0; r < 4; r++) {
            float v = vsum[i][r];
            v += __shfl_xor(v, 1, 16);
            v += __shfl_xor(v, 2, 16);
            v += __shfl_xor(v, 4, 16);
            v += __shfl_xor(v, 8, 16);
            vsum[i][r] = v;
        }

    if (colj == 0) {
        #pragma unroll
        for (int i = 0; i < 4; i++) {
            int n = n0 + w * 4 + i;
            float4 o;
            o.x = 0.5f * (vsum[i][0] + b3val);
            o.y = 0.5f * (vsum[i][1] + b3val);
            o.z = 0.5f * (vsum[i][2] + b3val);
            o.w = 0.5f * (vsum[i][3] + b3val);
            *(float4*)&V[(((size_t)p * NB + b) * NN + n) * MM + m0 + quad * 4] = o;
        }
    }
}

// ---------------------------------------------------------------------------
// k_finish: combine passes, softplus, reduce R^2 moments over m, then
// multilaterate and write flow (B,3,N). Grid (16 n-tiles, NB), 256 thr.
// ---------------------------------------------------------------------------
__global__ void k_finish(const float* __restrict__ V, const float* __restrict__ ancP,
                         const float* __restrict__ cst, const float* __restrict__ actP,
                         float* __restrict__ out)
{
    int b = blockIdx.y;
    int n = blockIdx.x * 16 + (threadIdx.x >> 4);
    int ml = threadIdx.x & 15;
    const float* v0 = V + (((size_t)0 * NB + b) * NN + n) * MM;
    const float* v1 = V + (((size_t)1 * NB + b) * NN + n) * MM;
    float s0 = 0.f, s1 = 0.f, s2 = 0.f, s3 = 0.f;
    #pragma unroll
    for (int k = 0; k < 16; k++) {
        int m = ml + k * 16;
        float x = v0[m] + v1[m];
        float R = fmaxf(x, 0.f) + log1pf(expf(-fabsf(x)));
        float r2 = R * R;
        float px = ancP[b*3*MM + 0*MM + m];
        float py = ancP[b*3*MM + 1*MM + m];
        float pz = ancP[b*3*MM + 2*MM + m];
        s0 = fmaf(r2, px, s0);
        s1 = fmaf(r2, py, s1);
        s2 = fmaf(r2, pz, s2);
        s3 += r2;
    }
    #pragma unroll
    for (int off = 8; off >= 1; off >>= 1) {
        s0 += __shfl_xor(s0, off, 16);
        s1 += __shfl_xor(s1, off, 16);
        s2 += __shfl_xor(s2, off, 16);
        s3 += __shfl_xor(s3, off, 16);
    }
    if (ml == 0) {
        const float* C = cst + b*32;
        float c0=C[0], c1=C[1], c2=C[2];
        float t0x=C[12], t0y=C[13], t0z=C[14];
        float cc=C[15];
        float SnP0=C[16], SnP1=C[17], SnP2=C[18], Sn=C[19];

        const float invM = 1.0f / MM;
        float a0 = SnP0 - s0*invM;
        float a1 = SnP1 - s1*invM;
        float a2 = SnP2 - s2*invM;
        float mWd = Sn - s3*invM;

        float f0 = a0 + t0x - mWd*c0 + 2.0f*cc*c0;
        float f1 = a1 + t0y - mWd*c1 + 2.0f*cc*c1;
        float f2 = a2 + t0z - mWd*c2 + 2.0f*cc*c2;

        float q0 = -(C[3]*f0 + C[4]*f1 + C[5]*f2);
        float q1 = -(C[6]*f0 + C[7]*f1 + C[8]*f2);
        float q2 = -(C[9]*f0 + C[10]*f1 + C[11]*f2);

        float p0 = q0 + c0, p1 = q1 + c1, p2 = q2 + c2;

        out[b*3*NN + 0*NN + n] = p0 - actP[b*3*NN + 0*NN + n];
        out[b*3*NN + 1*NN + n] = p1 - actP[b*3*NN + 1*NN + n];
        out[b*3*NN + 2*NN + n] = p2 - actP[b*3*NN + 2*NN + n];
    }
}

extern "C" void kernel_launch(void* const* d_in, const int* in_sizes, int n_in,
                              void* d_out, int out_size, void* d_ws, size_t ws_size,
                              hipStream_t stream)
{
    const float* actE = (const float*)d_in[0];
    const float* ancE = (const float*)d_in[1];
    const float* actP = (const float*)d_in[2];
    const float* ancP = (const float*)d_in[3];
    const float* W1   = (const float*)d_in[4];
    const float* b1   = (const float*)d_in[5];
    const float* W2   = (const float*)d_in[6];
    const float* b2   = (const float*)d_in[7];
    const float* W3   = (const float*)d_in[8];
    const float* b3   = (const float*)d_in[9];
    float* ws  = (float*)d_ws;
    float* out = (float*)d_out;

    k_setup <<<850, 256, 0, stream>>>(W1, W2, b2, W3, actE, ancE, ancP, ws);
    k_hidden<<<dim3(16, 10, 4), 256, 0, stream>>>(ws, b1);
    k_pair  <<<dim3(16, 16, NB*2), 256, 0, stream>>>(ws, b3, ws + OFF_V);
    k_finish<<<dim3(16, NB), 256, 0, stream>>>(ws + OFF_V, ancP, ws + OFF_CST, actP, out);
}